// Round 15
// baseline (536.857 us; speedup 1.0000x reference)
//
#include <hip/hip_runtime.h>

#define EPS_LN 1e-5f

typedef __attribute__((ext_vector_type(4))) float f32x4;
typedef __attribute__((ext_vector_type(4))) int i32x4;

// ---------------------------------------------------------------------------
// bf16 helpers
__device__ inline unsigned short f2bf_rne(float x) {
  unsigned int u = __float_as_uint(x);
  unsigned int r = u + 0x7fffu + ((u >> 16) & 1u);
  return (unsigned short)(r >> 16);
}

__device__ inline float4 bf4_to_f4(uint2 u) {
  float4 f;
  f.x = __uint_as_float(u.x << 16);
  f.y = __uint_as_float(u.x & 0xffff0000u);
  f.z = __uint_as_float(u.y << 16);
  f.w = __uint_as_float(u.y & 0xffff0000u);
  return f;
}

__device__ inline uint2 f4_to_bf4(float4 v) {
  uint2 o;
  o.x = (unsigned)f2bf_rne(v.x) | ((unsigned)f2bf_rne(v.y) << 16);
  o.y = (unsigned)f2bf_rne(v.z) | ((unsigned)f2bf_rne(v.w) << 16);
  return o;
}

__device__ inline void split_bf16(float x, unsigned short& hi, unsigned short& lo) {
  unsigned int bits = __float_as_uint(x);
  hi = (unsigned short)(bits >> 16);
  float hif = __uint_as_float((unsigned int)hi << 16);
  float res = x - hif;
  lo = (unsigned short)(__float_as_uint(res) >> 16);
}

__device__ inline void mfma_b16(f32x4& acc, i32x4 a, i32x4 b) {
  asm volatile("v_mfma_f32_16x16x32_bf16 %0, %1, %2, %0"
               : "+v"(acc)
               : "v"(a), "v"(b));
}

// ---------------------------------------------------------------------------
// one-shot split of all weight matrices into bf16 hi/lo planes (args)
struct SplitWArgs {
  const float* src[12];
  unsigned short* dh[12];
  unsigned short* dl[12];
  int n[12];
};

// prep1: sections {copy_bf16 | hist | WpP=W10@We2d | WsP=W12@We2d}
struct Prep1Args {
  const float4* x4; uint2* h_out; int n4; int cb_blocks;
  const int* dst; int* deg; int nE; int hist_blocks;
  const float* W10; const float* We2d; float* WpP;
  const float* W12; float* WsP;
};

__global__ __launch_bounds__(256) void prep1_kernel(Prep1Args a) {
  int b = blockIdx.x;
  int tid = threadIdx.x;
  if (b < a.cb_blocks) {  // x f32 -> h bf16
    int i = b * 256 + tid;
    if (i < a.n4) a.h_out[i] = f4_to_bf4(a.x4[i]);
    return;
  }
  b -= a.cb_blocks;
  if (b < a.hist_blocks) {  // deg histogram
    int e = b * 256 + tid;
    if (e < a.nE) atomicAdd(a.deg + a.dst[e], 1);
    return;
  }
  b -= a.hist_blocks;
  if (b < 16) {  // WpP[64][64] = W10[64][64] @ We2d[64][64]
    int idx = b * 256 + tid;
    if (idx < 64 * 64) {
      int o = idx >> 6, i = idx & 63;
      float s = 0.f;
      for (int k = 0; k < 64; ++k) s += a.W10[o * 64 + k] * a.We2d[k * 64 + i];
      a.WpP[idx] = s;
    }
    return;
  }
  b -= 16;
  {  // WsP[96][64] = W12[96][64] @ We2d[64][64]
    int idx = b * 256 + tid;
    if (idx < 96 * 64) {
      int o = idx >> 6, i = idx & 63;
      float s = 0.f;
      for (int k = 0; k < 64; ++k) s += a.W12[o * 64 + k] * a.We2d[k * 64 + i];
      a.WsP[idx] = s;
    }
  }
}

// prep2: sections {blocksum | mask_scatter | split_w}
#define SCAN_CHUNK 1024

struct Prep2Args {
  const int* deg; int* bsum; int n; int nb;
  const int* mn; const float* token; unsigned short* H; int nmask; int ms_blocks;
  SplitWArgs sw;
  int boff[13];
};

__global__ __launch_bounds__(256) void prep2_kernel(Prep2Args a) {
  __shared__ int red[256];
  int b = blockIdx.x;
  int tid = threadIdx.x;
  if (b < a.nb) {  // per-chunk degree sums
    int base = b * SCAN_CHUNK;
    int s = 0;
#pragma unroll
    for (int t = 0; t < SCAN_CHUNK / 256; ++t) {
      int g = base + tid + t * 256;
      if (g < a.n) s += a.deg[g];
    }
    red[tid] = s;
    __syncthreads();
    for (int ofs = 128; ofs > 0; ofs >>= 1) {
      if (tid < ofs) red[tid] += red[tid + ofs];
      __syncthreads();
    }
    if (tid == 0) a.bsum[b] = red[0];
    return;
  }
  b -= a.nb;
  if (b < a.ms_blocks) {  // mask token scatter into bf16 H
    int gid = b * 256 + tid;
    if (gid >= a.nmask * 32) return;
    int i = gid >> 5;
    int c4 = (gid & 31) << 2;
    int r = a.mn[i];
    float4 t = *(const float4*)(a.token + c4);
    *(uint2*)(a.H + (size_t)r * 128 + c4) = f4_to_bf4(t);
    return;
  }
  b -= a.ms_blocks;
  {  // split weights into hi/lo planes
    int m = 0;
    while (m < 11 && b >= a.boff[m + 1]) ++m;
    int i = ((b - a.boff[m]) * 256 + tid) * 4;
    if (i >= a.sw.n[m]) return;
    float4 v = *(const float4*)(a.sw.src[m] + i);
    unsigned short h[4], l[4];
    split_bf16(v.x, h[0], l[0]);
    split_bf16(v.y, h[1], l[1]);
    split_bf16(v.z, h[2], l[2]);
    split_bf16(v.w, h[3], l[3]);
    *(uint2*)(a.sw.dh[m] + i) = make_uint2((unsigned)h[0] | ((unsigned)h[1] << 16),
                                           (unsigned)h[2] | ((unsigned)h[3] << 16));
    *(uint2*)(a.sw.dl[m] + i) = make_uint2((unsigned)l[0] | ((unsigned)l[1] << 16),
                                           (unsigned)l[2] | ((unsigned)l[3] << 16));
  }
}

// ---------------------------------------------------------------------------
__global__ __launch_bounds__(64) void bscan_kernel(const int* __restrict__ bsum,
                                                   int* __restrict__ bbase,
                                                   int* __restrict__ off_n, int nb) {
  int tid = threadIdx.x;
  int v = (tid < nb) ? bsum[tid] : 0;
  int incl = v;
#pragma unroll
  for (int ofs = 1; ofs < 64; ofs <<= 1) {
    int u = __shfl_up(incl, ofs, 64);
    if (tid >= ofs) incl += u;
  }
  if (tid < nb) bbase[tid] = incl - v;
  if (tid == nb - 1) off_n[0] = incl;
}

__global__ __launch_bounds__(256) void chunkscan_kernel(const int* __restrict__ deg,
                                                        const int* __restrict__ bbase,
                                                        int* __restrict__ off, int n) {
  __shared__ int part[256];
  int tid = threadIdx.x;
  int base = blockIdx.x * SCAN_CHUNK;
  int g0 = base + tid * 4;
  int loc[4];
  int s = 0;
#pragma unroll
  for (int j = 0; j < 4; ++j) {
    int g = g0 + j;
    int d = (g < n) ? deg[g] : 0;
    loc[j] = s;
    s += d;
  }
  part[tid] = s;
  __syncthreads();
  for (int ofs = 1; ofs < 256; ofs <<= 1) {
    int v = 0;
    if (tid >= ofs) v = part[tid - ofs];
    __syncthreads();
    if (tid >= ofs) part[tid] += v;
    __syncthreads();
  }
  int pre = (tid == 0) ? 0 : part[tid - 1];
  int b = bbase[blockIdx.x] + pre;
#pragma unroll
  for (int j = 0; j < 4; ++j) {
    int g = g0 + j;
    if (g < n) off[g] = b + loc[j];
  }
}

// scatter edges into dst-sorted order (single-phase, per-node atomics)
__global__ __launch_bounds__(256) void scatter_kernel(const int* __restrict__ src,
                                                      const int* __restrict__ dst,
                                                      const float* __restrict__ ew,
                                                      const int* __restrict__ off,
                                                      int* __restrict__ cur,
                                                      int2* __restrict__ esw, int nE) {
  int e = blockIdx.x * 256 + threadIdx.x;
  if (e >= nE) return;
  int d = dst[e];
  int pos = off[d] + atomicAdd(cur + d, 1);
  esw[pos] = make_int2(src[e], __float_as_int(ew[e]));
}

// ---------------------------------------------------------------------------
// per-node segment max over CSR, bf16 P -> bf16 neigh, f32 math.
// din/8 lanes per node, one uint4 (8 bf16) per lane. 4 independent chains.
__global__ __launch_bounds__(256) void neigh_csr_kernel(
    const unsigned short* __restrict__ P, const int* __restrict__ off,
    const int2* __restrict__ esw,
    unsigned short* __restrict__ neigh, int din, int lanes, int nN) {
  int gid = blockIdx.x * 256 + threadIdx.x;
  int v = gid / lanes;
  int c = (gid - v * lanes) << 3;
  if (v >= nN) return;
  int jlo = off[v], jhi = off[v + 1];
  float m[8];
#pragma unroll
  for (int t = 0; t < 8; ++t) m[t] = 0.f;
  float n1[8], n2[8], n3[8];
#pragma unroll
  for (int t = 0; t < 8; ++t) { n1[t] = 0.f; n2[t] = 0.f; n3[t] = 0.f; }
  int j = jlo;
  for (; j + 4 <= jhi; j += 4) {
    int2 e0 = esw[j], e1 = esw[j + 1], e2 = esw[j + 2], e3 = esw[j + 3];
    uint4 q0 = *(const uint4*)(P + (size_t)e0.x * din + c);
    uint4 q1 = *(const uint4*)(P + (size_t)e1.x * din + c);
    uint4 q2 = *(const uint4*)(P + (size_t)e2.x * din + c);
    uint4 q3 = *(const uint4*)(P + (size_t)e3.x * din + c);
    float w0 = __int_as_float(e0.y), w1 = __int_as_float(e1.y);
    float w2 = __int_as_float(e2.y), w3 = __int_as_float(e3.y);
    float4 a0 = bf4_to_f4(make_uint2(q0.x, q0.y)), b0 = bf4_to_f4(make_uint2(q0.z, q0.w));
    float4 a1 = bf4_to_f4(make_uint2(q1.x, q1.y)), b1 = bf4_to_f4(make_uint2(q1.z, q1.w));
    float4 a2 = bf4_to_f4(make_uint2(q2.x, q2.y)), b2 = bf4_to_f4(make_uint2(q2.z, q2.w));
    float4 a3 = bf4_to_f4(make_uint2(q3.x, q3.y)), b3 = bf4_to_f4(make_uint2(q3.z, q3.w));
    m[0] = fmaxf(m[0], a0.x * w0); m[1] = fmaxf(m[1], a0.y * w0);
    m[2] = fmaxf(m[2], a0.z * w0); m[3] = fmaxf(m[3], a0.w * w0);
    m[4] = fmaxf(m[4], b0.x * w0); m[5] = fmaxf(m[5], b0.y * w0);
    m[6] = fmaxf(m[6], b0.z * w0); m[7] = fmaxf(m[7], b0.w * w0);
    n1[0] = fmaxf(n1[0], a1.x * w1); n1[1] = fmaxf(n1[1], a1.y * w1);
    n1[2] = fmaxf(n1[2], a1.z * w1); n1[3] = fmaxf(n1[3], a1.w * w1);
    n1[4] = fmaxf(n1[4], b1.x * w1); n1[5] = fmaxf(n1[5], b1.y * w1);
    n1[6] = fmaxf(n1[6], b1.z * w1); n1[7] = fmaxf(n1[7], b1.w * w1);
    n2[0] = fmaxf(n2[0], a2.x * w2); n2[1] = fmaxf(n2[1], a2.y * w2);
    n2[2] = fmaxf(n2[2], a2.z * w2); n2[3] = fmaxf(n2[3], a2.w * w2);
    n2[4] = fmaxf(n2[4], b2.x * w2); n2[5] = fmaxf(n2[5], b2.y * w2);
    n2[6] = fmaxf(n2[6], b2.z * w2); n2[7] = fmaxf(n2[7], b2.w * w2);
    n3[0] = fmaxf(n3[0], a3.x * w3); n3[1] = fmaxf(n3[1], a3.y * w3);
    n3[2] = fmaxf(n3[2], a3.z * w3); n3[3] = fmaxf(n3[3], a3.w * w3);
    n3[4] = fmaxf(n3[4], b3.x * w3); n3[5] = fmaxf(n3[5], b3.y * w3);
    n3[6] = fmaxf(n3[6], b3.z * w3); n3[7] = fmaxf(n3[7], b3.w * w3);
  }
  for (; j < jhi; ++j) {
    int2 e = esw[j];
    float w = __int_as_float(e.y);
    uint4 q = *(const uint4*)(P + (size_t)e.x * din + c);
    float4 a = bf4_to_f4(make_uint2(q.x, q.y)), b = bf4_to_f4(make_uint2(q.z, q.w));
    m[0] = fmaxf(m[0], a.x * w); m[1] = fmaxf(m[1], a.y * w);
    m[2] = fmaxf(m[2], a.z * w); m[3] = fmaxf(m[3], a.w * w);
    m[4] = fmaxf(m[4], b.x * w); m[5] = fmaxf(m[5], b.y * w);
    m[6] = fmaxf(m[6], b.z * w); m[7] = fmaxf(m[7], b.w * w);
  }
#pragma unroll
  for (int t = 0; t < 8; ++t) m[t] = fmaxf(fmaxf(m[t], n1[t]), fmaxf(n2[t], n3[t]));
  uint2 o0 = f4_to_bf4(make_float4(m[0], m[1], m[2], m[3]));
  uint2 o1 = f4_to_bf4(make_float4(m[4], m[5], m[6], m[7]));
  *(uint4*)(neigh + (size_t)v * din + c) = make_uint4(o0.x, o0.y, o1.x, o1.y);
}

// ---------------------------------------------------------------------------
// MFMA GEMM, bf16 activations (standalone; used for enc0's p only).
template <int TNT>  // BN = TNT*16
__global__ __launch_bounds__(256) void mfma_gemm_kernel(
    const unsigned short* __restrict__ A1, const unsigned short* __restrict__ Wh1,
    const unsigned short* __restrict__ Wl1, int k1,
    const float* __restrict__ bias,
    unsigned short* __restrict__ C, int nrows) {
  constexpr int BN = TNT * 16;
  constexpr int WS = 136;
  __shared__ __align__(16) unsigned short Wh[BN][WS];
  __shared__ __align__(16) unsigned short Wl[BN][WS];

  const int tid = threadIdx.x;
  const int lane = tid & 63;
  const int wv = tid >> 6;
  const int lr = lane & 15;
  const int lg = lane >> 4;
  const int row0 = blockIdx.x * 64;
  const int gra = row0 + wv * 16 + lr;

  f32x4 acc[TNT];
#pragma unroll
  for (int t = 0; t < TNT; ++t) acc[t] = (f32x4)(0.f);

  {
    int tot8 = BN * k1 / 8;
    for (int i = tid; i < tot8; i += 256) {
      int e0 = i * 8;
      int col = e0 / k1;
      int kk = e0 - col * k1;
      *(uint4*)&Wh[col][kk] = *(const uint4*)(Wh1 + e0);
      *(uint4*)&Wl[col][kk] = *(const uint4*)(Wl1 + e0);
    }
  }
  __syncthreads();

  for (int cb = 0; cb < k1; cb += 32) {
    i32x4 a_h = (i32x4)(0);
    if (gra < nrows) a_h = *(const i32x4*)(A1 + (size_t)gra * k1 + cb + lg * 8);
#pragma unroll
    for (int t = 0; t < TNT; ++t) {
      i32x4 b_h = *(const i32x4*)&Wh[t * 16 + lr][cb + lg * 8];
      i32x4 b_l = *(const i32x4*)&Wl[t * 16 + lr][cb + lg * 8];
      mfma_b16(acc[t], a_h, b_h);
      mfma_b16(acc[t], a_h, b_l);
    }
  }

  asm volatile("s_nop 7\n\ts_nop 7" ::);

#pragma unroll
  for (int t = 0; t < TNT; ++t) {
    int c = t * 16 + lr;
    float bv = bias[c];
#pragma unroll
    for (int q = 0; q < 4; ++q) {
      int r = row0 + wv * 16 + lg * 4 + q;
      if (r < nrows) {
        float v = fmaxf(acc[t][q] + bv, 0.f);
        C[(size_t)r * BN + c] = f2bf_rne(v);
      }
    }
  }
}

// ---------------------------------------------------------------------------
// Fused SAGE out-GEMM + next-layer p-GEMM.
// Phase 1/2: C = relu(A1@W1^T + A2@W2^T + bias)  (A from global, W in LDS)
// Phase 3 (if P_out): P_out = relu(C@Wp^T + pBias), A re-read from C (L2-hot),
//   Wp planes restaged into the same LDS. Wp is square [BN][BN].
template <int TNT>  // BN = TNT*16
__global__ __launch_bounds__(256) void mfma_gemm_fused_kernel(
    const unsigned short* __restrict__ A1, const unsigned short* __restrict__ Wh1,
    const unsigned short* __restrict__ Wl1,
    const unsigned short* __restrict__ A2, const unsigned short* __restrict__ Wh2,
    const unsigned short* __restrict__ Wl2, int K,
    const float* __restrict__ bias, unsigned short* __restrict__ C,
    const unsigned short* __restrict__ pWh, const unsigned short* __restrict__ pWl,
    const float* __restrict__ pBias, unsigned short* __restrict__ P_out,
    int nrows) {
  constexpr int BN = TNT * 16;
  constexpr int WS = 136;
  __shared__ __align__(16) unsigned short Wh[BN][WS];
  __shared__ __align__(16) unsigned short Wl[BN][WS];

  const int tid = threadIdx.x;
  const int lane = tid & 63;
  const int wv = tid >> 6;
  const int lr = lane & 15;
  const int lg = lane >> 4;
  const int row0 = blockIdx.x * 64;
  const int gra = row0 + wv * 16 + lr;

  f32x4 acc[TNT];
#pragma unroll
  for (int t = 0; t < TNT; ++t) acc[t] = (f32x4)(0.f);

  for (int pass = 0; pass < 2; ++pass) {
    const unsigned short* A = pass ? A2 : A1;
    const unsigned short* Whp = pass ? Wh2 : Wh1;
    const unsigned short* Wlp = pass ? Wl2 : Wl1;

    if (pass) __syncthreads();
    {
      int tot8 = BN * K / 8;
      for (int i = tid; i < tot8; i += 256) {
        int e0 = i * 8;
        int col = e0 / K;
        int kk = e0 - col * K;
        *(uint4*)&Wh[col][kk] = *(const uint4*)(Whp + e0);
        *(uint4*)&Wl[col][kk] = *(const uint4*)(Wlp + e0);
      }
    }
    __syncthreads();

    for (int cb = 0; cb < K; cb += 32) {
      i32x4 a_h = (i32x4)(0);
      if (gra < nrows) a_h = *(const i32x4*)(A + (size_t)gra * K + cb + lg * 8);
#pragma unroll
      for (int t = 0; t < TNT; ++t) {
        i32x4 b_h = *(const i32x4*)&Wh[t * 16 + lr][cb + lg * 8];
        i32x4 b_l = *(const i32x4*)&Wl[t * 16 + lr][cb + lg * 8];
        mfma_b16(acc[t], a_h, b_h);
        mfma_b16(acc[t], a_h, b_l);
      }
    }
  }

  asm volatile("s_nop 7\n\ts_nop 7" ::);

#pragma unroll
  for (int t = 0; t < TNT; ++t) {
    int c = t * 16 + lr;
    float bv = bias[c];
#pragma unroll
    for (int q = 0; q < 4; ++q) {
      int r = row0 + wv * 16 + lg * 4 + q;
      if (r < nrows) {
        float v = fmaxf(acc[t][q] + bv, 0.f);
        C[(size_t)r * BN + c] = f2bf_rne(v);
      }
    }
  }

  if (P_out == nullptr) return;

  // ---- phase 3: p_next = relu(C @ Wp^T + pBias), K_p = BN ----
  __threadfence();   // make this block's C stores L2-visible
  __syncthreads();
  {
    int tot8 = BN * BN / 8;
    for (int i = tid; i < tot8; i += 256) {
      int e0 = i * 8;
      int col = e0 / BN;
      int kk = e0 - col * BN;
      *(uint4*)&Wh[col][kk] = *(const uint4*)(pWh + e0);
      *(uint4*)&Wl[col][kk] = *(const uint4*)(pWl + e0);
    }
  }
  __syncthreads();

#pragma unroll
  for (int t = 0; t < TNT; ++t) acc[t] = (f32x4)(0.f);

  for (int cb = 0; cb < BN; cb += 32) {
    i32x4 a_h = (i32x4)(0);
    if (gra < nrows) a_h = *(const i32x4*)(C + (size_t)gra * BN + cb + lg * 8);
#pragma unroll
    for (int t = 0; t < TNT; ++t) {
      i32x4 b_h = *(const i32x4*)&Wh[t * 16 + lr][cb + lg * 8];
      i32x4 b_l = *(const i32x4*)&Wl[t * 16 + lr][cb + lg * 8];
      mfma_b16(acc[t], a_h, b_h);
      mfma_b16(acc[t], a_h, b_l);
    }
  }

  asm volatile("s_nop 7\n\ts_nop 7" ::);

#pragma unroll
  for (int t = 0; t < TNT; ++t) {
    int c = t * 16 + lr;
    float bv = pBias[c];
#pragma unroll
    for (int q = 0; q < 4; ++q) {
      int r = row0 + wv * 16 + lg * 4 + q;
      if (r < nrows) {
        float v = fmaxf(acc[t][q] + bv, 0.f);
        P_out[(size_t)r * BN + c] = f2bf_rne(v);
      }
    }
  }
}

// ---------------------------------------------------------------------------
// z = H @ Wnp^T + bnp  (H: [n,64] bf16, Wnp: [16,64] f32) then LayerNorm(16)
__global__ __launch_bounds__(256) void nodepred_ln_kernel(
    const unsigned short* __restrict__ H, const float* __restrict__ Wnp,
    const float* __restrict__ bnp, const float* __restrict__ g,
    const float* __restrict__ lb, float* __restrict__ out, int nrows) {
  __shared__ float hs[16][64];
  int tid = threadIdx.x;
  int row0 = blockIdx.x * 16;
  {
    int r = tid >> 4;
    int c4 = (tid & 15) << 2;
    int gr = row0 + r;
    float4 v = make_float4(0.f, 0.f, 0.f, 0.f);
    if (gr < nrows) v = bf4_to_f4(*(const uint2*)(H + (size_t)gr * 64 + c4));
    *(float4*)&hs[r][c4] = v;
  }
  __syncthreads();
  int r = tid >> 4, j = tid & 15;
  float z = bnp[j];
  const float* wrow = Wnp + j * 64;
#pragma unroll 8
  for (int k = 0; k < 64; ++k) z += hs[r][k] * wrow[k];
  float s = z, s2 = z * z;
#pragma unroll
  for (int m = 1; m < 16; m <<= 1) {
    s += __shfl_xor(s, m, 16);
    s2 += __shfl_xor(s2, m, 16);
  }
  float mu = s * (1.f / 16.f);
  float var = s2 * (1.f / 16.f) - mu * mu;
  float o = (z - mu) * rsqrtf(var + EPS_LN) * g[j] + lb[j];
  int gr = row0 + r;
  if (gr < nrows) out[(size_t)gr * 16 + j] = o;
}

// ---------------------------------------------------------------------------
// out1[i] = f32(R_bf16[mn[i]]), out2[i] = X_f32[mn[i]]   (rows of 128)
__global__ __launch_bounds__(256) void gather_out_kernel(
    const int* __restrict__ mn, const unsigned short* __restrict__ R,
    const float* __restrict__ X,
    float* __restrict__ o1, float* __restrict__ o2, int nmask) {
  int gid = blockIdx.x * 256 + threadIdx.x;
  if (gid >= nmask * 32) return;
  int i = gid >> 5, c4 = (gid & 31) << 2;
  int r = mn[i];
  float4 rv = bf4_to_f4(*(const uint2*)(R + (size_t)r * 128 + c4));
  *(float4*)(o1 + (size_t)i * 128 + c4) = rv;
  *(float4*)(o2 + (size_t)i * 128 + c4) = *(const float4*)(X + (size_t)r * 128 + c4);
}

// ---------------------------------------------------------------------------
static void launch_fused(const unsigned short* A1, const unsigned short* Wh1,
                         const unsigned short* Wl1,
                         const unsigned short* A2, const unsigned short* Wh2,
                         const unsigned short* Wl2, int K,
                         const float* bias, unsigned short* C,
                         const unsigned short* pWh, const unsigned short* pWl,
                         const float* pBias, unsigned short* P_out,
                         int m, int nrows, hipStream_t s) {
  int blocks = (nrows + 63) / 64;
  switch (m) {
    case 128:
      mfma_gemm_fused_kernel<8><<<blocks, 256, 0, s>>>(A1, Wh1, Wl1, A2, Wh2, Wl2, K,
                                                       bias, C, pWh, pWl, pBias, P_out, nrows);
      break;
    case 96:
      mfma_gemm_fused_kernel<6><<<blocks, 256, 0, s>>>(A1, Wh1, Wl1, A2, Wh2, Wl2, K,
                                                       bias, C, pWh, pWl, pBias, P_out, nrows);
      break;
    case 64:
      mfma_gemm_fused_kernel<4><<<blocks, 256, 0, s>>>(A1, Wh1, Wl1, A2, Wh2, Wl2, K,
                                                       bias, C, pWh, pWl, pBias, P_out, nrows);
      break;
  }
}

extern "C" void kernel_launch(void* const* d_in, const int* in_sizes, int n_in,
                              void* d_out, int out_size, void* d_ws, size_t ws_size,
                              hipStream_t stream) {
  const float* x = (const float*)d_in[0];
  const int* src = (const int*)d_in[1];
  const int* dst = (const int*)d_in[2];
  const float* ew = (const float*)d_in[3];
  const int* mn = (const int*)d_in[4];
  const float* token = (const float*)d_in[5];

  const float* W[20];
  for (int i = 0; i < 20; ++i) W[i] = (const float*)d_in[6 + i];
  const float* W_e2d = (const float*)d_in[26];
  const float* Wnp = (const float*)d_in[27];
  const float* bnp = (const float*)d_in[28];
  const float* ln_g = (const float*)d_in[29];
  const float* ln_b = (const float*)d_in[30];

  const int Nn = in_sizes[0] / 128;   // 50000
  const int E = in_sizes[1];          // 600000
  const int nmask = in_sizes[4];      // 10000
  const int nb = (Nn + SCAN_CHUNK - 1) / SCAN_CHUNK;  // 49

  // workspace layout (bf16 activations)
  unsigned short* bufA = (unsigned short*)d_ws;            // N*128 bf16
  unsigned short* bufB = bufA + (size_t)Nn * 128;          // N*128 bf16
  unsigned short* pool16 = bufB + (size_t)Nn * 128;        // N*128 bf16
  unsigned short* neigh16 = pool16 + (size_t)Nn * 128;     // N*128 bf16
  int* deg = (int*)(neigh16 + (size_t)Nn * 128);           // N int
  int* cur = deg + Nn;                                     // N int
  int2* esw = (int2*)(cur + Nn);                           // E int2
  int* off = (int*)(esw + E);                              // N+1 int
  int* bsum = off + Nn + 1;                                // 64 int
  int* bbase = bsum + 64;                                  // 64 int
  float* WpP = (float*)(bbase + 64);                       // 64*64 f32
  float* WsP = WpP + 64 * 64;                              // 96*64 f32
  unsigned short* wplanes =
      (unsigned short*)(((uintptr_t)(WsP + 96 * 64) + 15) & ~(uintptr_t)15);

  // plane table
  const int msz[12] = {128 * 128, 96 * 128, 96 * 128, 96 * 96, 64 * 96, 64 * 96,
                       64 * 64,  96 * 64,  96 * 64,  96 * 96, 128 * 96, 128 * 96};
  const float* msrc[12] = {W[0], W[2], W[3], W[5], W[7], W[8],
                           WpP,  WsP,  W[13], W[15], W[17], W[18]};
  int mtot = 0;
  int moff[12];
  for (int i = 0; i < 12; ++i) { moff[i] = mtot; mtot += msz[i]; }
  unsigned short* wh_[12];
  unsigned short* wl_[12];
  for (int i = 0; i < 12; ++i) {
    wh_[i] = wplanes + moff[i];
    wl_[i] = wplanes + mtot + moff[i];
  }

  // ---- dispatch 1: zero deg+cur ----
  hipMemsetAsync(deg, 0, (size_t)Nn * 2 * sizeof(int), stream);

  // ---- dispatch 2: prep1 = {copy_bf16 | hist | WpP | WsP} ----
  Prep1Args p1;
  p1.x4 = (const float4*)x;
  p1.h_out = (uint2*)bufA;
  p1.n4 = Nn * 128 / 4;
  p1.cb_blocks = (p1.n4 + 255) / 256;
  p1.dst = dst;
  p1.deg = deg;
  p1.nE = E;
  p1.hist_blocks = (E + 255) / 256;
  p1.W10 = W[10]; p1.We2d = W_e2d; p1.WpP = WpP;
  p1.W12 = W[12]; p1.WsP = WsP;
  int p1_blocks = p1.cb_blocks + p1.hist_blocks + 16 + 24;
  prep1_kernel<<<p1_blocks, 256, 0, stream>>>(p1);

  // ---- dispatch 3: prep2 = {blocksum | mask_scatter | split_w} ----
  Prep2Args p2;
  p2.deg = deg; p2.bsum = bsum; p2.n = Nn; p2.nb = nb;
  p2.mn = mn; p2.token = token; p2.H = bufA; p2.nmask = nmask;
  p2.ms_blocks = (nmask * 32 + 255) / 256;
  for (int i = 0; i < 12; ++i) {
    p2.sw.src[i] = msrc[i];
    p2.sw.dh[i] = wh_[i];
    p2.sw.dl[i] = wl_[i];
    p2.sw.n[i] = msz[i];
  }
  p2.boff[0] = 0;
  for (int i = 0; i < 12; ++i) p2.boff[i + 1] = p2.boff[i] + (msz[i] / 4 + 255) / 256;
  int p2_blocks = p2.nb + p2.ms_blocks + p2.boff[12];
  prep2_kernel<<<p2_blocks, 256, 0, stream>>>(p2);

  // ---- CSR scan + scatter ----
  bscan_kernel<<<1, 64, 0, stream>>>(bsum, bbase, off + Nn, nb);
  chunkscan_kernel<<<nb, 256, 0, stream>>>(deg, bbase, off, Nn);
  scatter_kernel<<<(E + 255) / 256, 256, 0, stream>>>(src, dst, ew, off, cur, esw, E);

  int gblocks = (Nn + 63) / 64;

  // ---- enc0 p (standalone): pool = relu(h0 @ Wp0^T + b1), 128x128 ----
  mfma_gemm_kernel<8><<<gblocks, 256, 0, stream>>>(bufA, wh_[0], wl_[0], 128, W[1],
                                                   pool16, Nn);

  auto neigh = [&](int din) {
    int lanes = din >> 3;
    long long tot = (long long)Nn * lanes;
    int nblocks = (int)((tot + 255) / 256);
    neigh_csr_kernel<<<nblocks, 256, 0, stream>>>(pool16, off, esw, neigh16, din, lanes, Nn);
  };

  // ---- enc0: h1[96] = relu(h0@Ws+neigh@Wn+b) ; fused p_enc1 -> pool ----
  neigh(128);
  launch_fused(bufA, wh_[1], wl_[1], neigh16, wh_[2], wl_[2], 128, W[4], bufB,
               wh_[3], wl_[3], W[6], pool16, 96, Nn, stream);

  // ---- enc1: h2[64] ; fused p_dec0 (folded WpP) -> pool ----
  neigh(96);
  launch_fused(bufB, wh_[4], wl_[4], neigh16, wh_[5], wl_[5], 96, W[9], bufA,
               wh_[6], wl_[6], W[11], pool16, 64, Nn, stream);

  // node_pred + layernorm on h2 (before bufA is overwritten by dec1's out)
  float* out_r = (float*)d_out;
  float* out_x = out_r + (size_t)nmask * 128;
  float* out_ns = out_x + (size_t)nmask * 128;
  nodepred_ln_kernel<<<(Nn + 15) / 16, 256, 0, stream>>>(bufA, Wnp, bnp, ln_g, ln_b, out_ns, Nn);

  // ---- dec0: h3[96] = relu(h2@WsP+neigh@Wn+b) ; fused p_dec1 -> pool ----
  neigh(64);
  launch_fused(bufA, wh_[7], wl_[7], neigh16, wh_[8], wl_[8], 64, W[14], bufB,
               wh_[9], wl_[9], W[16], pool16, 96, Nn, stream);

  // ---- dec1: h4[128] (no fused p) ----
  neigh(96);
  launch_fused(bufB, wh_[10], wl_[10], neigh16, wh_[11], wl_[11], 96, W[19], bufA,
               nullptr, nullptr, nullptr, nullptr, 128, Nn, stream);

  // outputs 1 & 2
  gather_out_kernel<<<(nmask * 32 + 255) / 256, 256, 0, stream>>>(mn, bufA, x, out_r, out_x, nmask);
}

// Round 16
// 337.722 us; speedup vs baseline: 1.5896x; 1.5896x over previous
//
#include <hip/hip_runtime.h>

#define EPS_LN 1e-5f

typedef __attribute__((ext_vector_type(4))) float f32x4;
typedef __attribute__((ext_vector_type(4))) int i32x4;

// ---------------------------------------------------------------------------
// bf16 helpers
__device__ inline unsigned short f2bf_rne(float x) {
  unsigned int u = __float_as_uint(x);
  unsigned int r = u + 0x7fffu + ((u >> 16) & 1u);
  return (unsigned short)(r >> 16);
}

__device__ inline float4 bf4_to_f4(uint2 u) {
  float4 f;
  f.x = __uint_as_float(u.x << 16);
  f.y = __uint_as_float(u.x & 0xffff0000u);
  f.z = __uint_as_float(u.y << 16);
  f.w = __uint_as_float(u.y & 0xffff0000u);
  return f;
}

__device__ inline uint2 f4_to_bf4(float4 v) {
  uint2 o;
  o.x = (unsigned)f2bf_rne(v.x) | ((unsigned)f2bf_rne(v.y) << 16);
  o.y = (unsigned)f2bf_rne(v.z) | ((unsigned)f2bf_rne(v.w) << 16);
  return o;
}

__device__ inline void split_bf16(float x, unsigned short& hi, unsigned short& lo) {
  unsigned int bits = __float_as_uint(x);
  hi = (unsigned short)(bits >> 16);
  float hif = __uint_as_float((unsigned int)hi << 16);
  float res = x - hif;
  lo = (unsigned short)(__float_as_uint(res) >> 16);
}

__device__ inline void mfma_b16(f32x4& acc, i32x4 a, i32x4 b) {
  asm volatile("v_mfma_f32_16x16x32_bf16 %0, %1, %2, %0"
               : "+v"(acc)
               : "v"(a), "v"(b));
}

// ---------------------------------------------------------------------------
// one-shot split of all weight matrices into bf16 hi/lo planes (args)
struct SplitWArgs {
  const float* src[12];
  unsigned short* dh[12];
  unsigned short* dl[12];
  int n[12];
};

// prep1: sections {copy_bf16 | hist | WpP=W10@We2d | WsP=W12@We2d}
struct Prep1Args {
  const float4* x4; uint2* h_out; int n4; int cb_blocks;
  const int* dst; int* deg; int nE; int hist_blocks;
  const float* W10; const float* We2d; float* WpP;
  const float* W12; float* WsP;
};

__global__ __launch_bounds__(256) void prep1_kernel(Prep1Args a) {
  int b = blockIdx.x;
  int tid = threadIdx.x;
  if (b < a.cb_blocks) {  // x f32 -> h bf16
    int i = b * 256 + tid;
    if (i < a.n4) a.h_out[i] = f4_to_bf4(a.x4[i]);
    return;
  }
  b -= a.cb_blocks;
  if (b < a.hist_blocks) {  // deg histogram
    int e = b * 256 + tid;
    if (e < a.nE) atomicAdd(a.deg + a.dst[e], 1);
    return;
  }
  b -= a.hist_blocks;
  if (b < 16) {  // WpP[64][64] = W10[64][64] @ We2d[64][64]
    int idx = b * 256 + tid;
    if (idx < 64 * 64) {
      int o = idx >> 6, i = idx & 63;
      float s = 0.f;
      for (int k = 0; k < 64; ++k) s += a.W10[o * 64 + k] * a.We2d[k * 64 + i];
      a.WpP[idx] = s;
    }
    return;
  }
  b -= 16;
  {  // WsP[96][64] = W12[96][64] @ We2d[64][64]
    int idx = b * 256 + tid;
    if (idx < 96 * 64) {
      int o = idx >> 6, i = idx & 63;
      float s = 0.f;
      for (int k = 0; k < 64; ++k) s += a.W12[o * 64 + k] * a.We2d[k * 64 + i];
      a.WsP[idx] = s;
    }
  }
}

// prep2: sections {blocksum | mask_scatter | split_w}
#define SCAN_CHUNK 1024

struct Prep2Args {
  const int* deg; int* bsum; int n; int nb;
  const int* mn; const float* token; unsigned short* H; int nmask; int ms_blocks;
  SplitWArgs sw;
  int boff[13];
};

__global__ __launch_bounds__(256) void prep2_kernel(Prep2Args a) {
  __shared__ int red[256];
  int b = blockIdx.x;
  int tid = threadIdx.x;
  if (b < a.nb) {  // per-chunk degree sums
    int base = b * SCAN_CHUNK;
    int s = 0;
#pragma unroll
    for (int t = 0; t < SCAN_CHUNK / 256; ++t) {
      int g = base + tid + t * 256;
      if (g < a.n) s += a.deg[g];
    }
    red[tid] = s;
    __syncthreads();
    for (int ofs = 128; ofs > 0; ofs >>= 1) {
      if (tid < ofs) red[tid] += red[tid + ofs];
      __syncthreads();
    }
    if (tid == 0) a.bsum[b] = red[0];
    return;
  }
  b -= a.nb;
  if (b < a.ms_blocks) {  // mask token scatter into bf16 H
    int gid = b * 256 + tid;
    if (gid >= a.nmask * 32) return;
    int i = gid >> 5;
    int c4 = (gid & 31) << 2;
    int r = a.mn[i];
    float4 t = *(const float4*)(a.token + c4);
    *(uint2*)(a.H + (size_t)r * 128 + c4) = f4_to_bf4(t);
    return;
  }
  b -= a.ms_blocks;
  {  // split weights into hi/lo planes
    int m = 0;
    while (m < 11 && b >= a.boff[m + 1]) ++m;
    int i = ((b - a.boff[m]) * 256 + tid) * 4;
    if (i >= a.sw.n[m]) return;
    float4 v = *(const float4*)(a.sw.src[m] + i);
    unsigned short h[4], l[4];
    split_bf16(v.x, h[0], l[0]);
    split_bf16(v.y, h[1], l[1]);
    split_bf16(v.z, h[2], l[2]);
    split_bf16(v.w, h[3], l[3]);
    *(uint2*)(a.sw.dh[m] + i) = make_uint2((unsigned)h[0] | ((unsigned)h[1] << 16),
                                           (unsigned)h[2] | ((unsigned)h[3] << 16));
    *(uint2*)(a.sw.dl[m] + i) = make_uint2((unsigned)l[0] | ((unsigned)l[1] << 16),
                                           (unsigned)l[2] | ((unsigned)l[3] << 16));
  }
}

// ---------------------------------------------------------------------------
__global__ __launch_bounds__(64) void bscan_kernel(const int* __restrict__ bsum,
                                                   int* __restrict__ bbase,
                                                   int* __restrict__ off_n, int nb) {
  int tid = threadIdx.x;
  int v = (tid < nb) ? bsum[tid] : 0;
  int incl = v;
#pragma unroll
  for (int ofs = 1; ofs < 64; ofs <<= 1) {
    int u = __shfl_up(incl, ofs, 64);
    if (tid >= ofs) incl += u;
  }
  if (tid < nb) bbase[tid] = incl - v;
  if (tid == nb - 1) off_n[0] = incl;
}

__global__ __launch_bounds__(256) void chunkscan_kernel(const int* __restrict__ deg,
                                                        const int* __restrict__ bbase,
                                                        int* __restrict__ off, int n) {
  __shared__ int part[256];
  int tid = threadIdx.x;
  int base = blockIdx.x * SCAN_CHUNK;
  int g0 = base + tid * 4;
  int loc[4];
  int s = 0;
#pragma unroll
  for (int j = 0; j < 4; ++j) {
    int g = g0 + j;
    int d = (g < n) ? deg[g] : 0;
    loc[j] = s;
    s += d;
  }
  part[tid] = s;
  __syncthreads();
  for (int ofs = 1; ofs < 256; ofs <<= 1) {
    int v = 0;
    if (tid >= ofs) v = part[tid - ofs];
    __syncthreads();
    if (tid >= ofs) part[tid] += v;
    __syncthreads();
  }
  int pre = (tid == 0) ? 0 : part[tid - 1];
  int b = bbase[blockIdx.x] + pre;
#pragma unroll
  for (int j = 0; j < 4; ++j) {
    int g = g0 + j;
    if (g < n) off[g] = b + loc[j];
  }
}

// scatter edges into dst-sorted order (single-phase, per-node atomics)
__global__ __launch_bounds__(256) void scatter_kernel(const int* __restrict__ src,
                                                      const int* __restrict__ dst,
                                                      const float* __restrict__ ew,
                                                      const int* __restrict__ off,
                                                      int* __restrict__ cur,
                                                      int2* __restrict__ esw, int nE) {
  int e = blockIdx.x * 256 + threadIdx.x;
  if (e >= nE) return;
  int d = dst[e];
  int pos = off[d] + atomicAdd(cur + d, 1);
  esw[pos] = make_int2(src[e], __float_as_int(ew[e]));
}

// ---------------------------------------------------------------------------
// per-node segment max over CSR, bf16 P -> bf16 neigh, f32 math.
// din/8 lanes per node, one uint4 (8 bf16) per lane. 4 independent chains.
__global__ __launch_bounds__(256) void neigh_csr_kernel(
    const unsigned short* __restrict__ P, const int* __restrict__ off,
    const int2* __restrict__ esw,
    unsigned short* __restrict__ neigh, int din, int lanes, int nN) {
  int gid = blockIdx.x * 256 + threadIdx.x;
  int v = gid / lanes;
  int c = (gid - v * lanes) << 3;
  if (v >= nN) return;
  int jlo = off[v], jhi = off[v + 1];
  float m[8];
#pragma unroll
  for (int t = 0; t < 8; ++t) m[t] = 0.f;
  float n1[8], n2[8], n3[8];
#pragma unroll
  for (int t = 0; t < 8; ++t) { n1[t] = 0.f; n2[t] = 0.f; n3[t] = 0.f; }
  int j = jlo;
  for (; j + 4 <= jhi; j += 4) {
    int2 e0 = esw[j], e1 = esw[j + 1], e2 = esw[j + 2], e3 = esw[j + 3];
    uint4 q0 = *(const uint4*)(P + (size_t)e0.x * din + c);
    uint4 q1 = *(const uint4*)(P + (size_t)e1.x * din + c);
    uint4 q2 = *(const uint4*)(P + (size_t)e2.x * din + c);
    uint4 q3 = *(const uint4*)(P + (size_t)e3.x * din + c);
    float w0 = __int_as_float(e0.y), w1 = __int_as_float(e1.y);
    float w2 = __int_as_float(e2.y), w3 = __int_as_float(e3.y);
    float4 a0 = bf4_to_f4(make_uint2(q0.x, q0.y)), b0 = bf4_to_f4(make_uint2(q0.z, q0.w));
    float4 a1 = bf4_to_f4(make_uint2(q1.x, q1.y)), b1 = bf4_to_f4(make_uint2(q1.z, q1.w));
    float4 a2 = bf4_to_f4(make_uint2(q2.x, q2.y)), b2 = bf4_to_f4(make_uint2(q2.z, q2.w));
    float4 a3 = bf4_to_f4(make_uint2(q3.x, q3.y)), b3 = bf4_to_f4(make_uint2(q3.z, q3.w));
    m[0] = fmaxf(m[0], a0.x * w0); m[1] = fmaxf(m[1], a0.y * w0);
    m[2] = fmaxf(m[2], a0.z * w0); m[3] = fmaxf(m[3], a0.w * w0);
    m[4] = fmaxf(m[4], b0.x * w0); m[5] = fmaxf(m[5], b0.y * w0);
    m[6] = fmaxf(m[6], b0.z * w0); m[7] = fmaxf(m[7], b0.w * w0);
    n1[0] = fmaxf(n1[0], a1.x * w1); n1[1] = fmaxf(n1[1], a1.y * w1);
    n1[2] = fmaxf(n1[2], a1.z * w1); n1[3] = fmaxf(n1[3], a1.w * w1);
    n1[4] = fmaxf(n1[4], b1.x * w1); n1[5] = fmaxf(n1[5], b1.y * w1);
    n1[6] = fmaxf(n1[6], b1.z * w1); n1[7] = fmaxf(n1[7], b1.w * w1);
    n2[0] = fmaxf(n2[0], a2.x * w2); n2[1] = fmaxf(n2[1], a2.y * w2);
    n2[2] = fmaxf(n2[2], a2.z * w2); n2[3] = fmaxf(n2[3], a2.w * w2);
    n2[4] = fmaxf(n2[4], b2.x * w2); n2[5] = fmaxf(n2[5], b2.y * w2);
    n2[6] = fmaxf(n2[6], b2.z * w2); n2[7] = fmaxf(n2[7], b2.w * w2);
    n3[0] = fmaxf(n3[0], a3.x * w3); n3[1] = fmaxf(n3[1], a3.y * w3);
    n3[2] = fmaxf(n3[2], a3.z * w3); n3[3] = fmaxf(n3[3], a3.w * w3);
    n3[4] = fmaxf(n3[4], b3.x * w3); n3[5] = fmaxf(n3[5], b3.y * w3);
    n3[6] = fmaxf(n3[6], b3.z * w3); n3[7] = fmaxf(n3[7], b3.w * w3);
  }
  for (; j < jhi; ++j) {
    int2 e = esw[j];
    float w = __int_as_float(e.y);
    uint4 q = *(const uint4*)(P + (size_t)e.x * din + c);
    float4 a = bf4_to_f4(make_uint2(q.x, q.y)), b = bf4_to_f4(make_uint2(q.z, q.w));
    m[0] = fmaxf(m[0], a.x * w); m[1] = fmaxf(m[1], a.y * w);
    m[2] = fmaxf(m[2], a.z * w); m[3] = fmaxf(m[3], a.w * w);
    m[4] = fmaxf(m[4], b.x * w); m[5] = fmaxf(m[5], b.y * w);
    m[6] = fmaxf(m[6], b.z * w); m[7] = fmaxf(m[7], b.w * w);
  }
#pragma unroll
  for (int t = 0; t < 8; ++t) m[t] = fmaxf(fmaxf(m[t], n1[t]), fmaxf(n2[t], n3[t]));
  uint2 o0 = f4_to_bf4(make_float4(m[0], m[1], m[2], m[3]));
  uint2 o1 = f4_to_bf4(make_float4(m[4], m[5], m[6], m[7]));
  *(uint4*)(neigh + (size_t)v * din + c) = make_uint4(o0.x, o0.y, o1.x, o1.y);
}

// ---------------------------------------------------------------------------
// MFMA GEMM, bf16 activations (standalone; used for enc0's p only).
template <int TNT>  // BN = TNT*16
__global__ __launch_bounds__(256) void mfma_gemm_kernel(
    const unsigned short* __restrict__ A1, const unsigned short* __restrict__ Wh1,
    const unsigned short* __restrict__ Wl1, int k1,
    const float* __restrict__ bias,
    unsigned short* __restrict__ C, int nrows) {
  constexpr int BN = TNT * 16;
  constexpr int WS = 136;
  __shared__ __align__(16) unsigned short Wh[BN][WS];
  __shared__ __align__(16) unsigned short Wl[BN][WS];

  const int tid = threadIdx.x;
  const int lane = tid & 63;
  const int wv = tid >> 6;
  const int lr = lane & 15;
  const int lg = lane >> 4;
  const int row0 = blockIdx.x * 64;
  const int gra = row0 + wv * 16 + lr;

  f32x4 acc[TNT];
#pragma unroll
  for (int t = 0; t < TNT; ++t) acc[t] = (f32x4)(0.f);

  {
    int tot8 = BN * k1 / 8;
    for (int i = tid; i < tot8; i += 256) {
      int e0 = i * 8;
      int col = e0 / k1;
      int kk = e0 - col * k1;
      *(uint4*)&Wh[col][kk] = *(const uint4*)(Wh1 + e0);
      *(uint4*)&Wl[col][kk] = *(const uint4*)(Wl1 + e0);
    }
  }
  __syncthreads();

  for (int cb = 0; cb < k1; cb += 32) {
    i32x4 a_h = (i32x4)(0);
    if (gra < nrows) a_h = *(const i32x4*)(A1 + (size_t)gra * k1 + cb + lg * 8);
#pragma unroll
    for (int t = 0; t < TNT; ++t) {
      i32x4 b_h = *(const i32x4*)&Wh[t * 16 + lr][cb + lg * 8];
      i32x4 b_l = *(const i32x4*)&Wl[t * 16 + lr][cb + lg * 8];
      mfma_b16(acc[t], a_h, b_h);
      mfma_b16(acc[t], a_h, b_l);
    }
  }

  asm volatile("s_nop 7\n\ts_nop 7" ::);

#pragma unroll
  for (int t = 0; t < TNT; ++t) {
    int c = t * 16 + lr;
    float bv = bias[c];
#pragma unroll
    for (int q = 0; q < 4; ++q) {
      int r = row0 + wv * 16 + lg * 4 + q;
      if (r < nrows) {
        float v = fmaxf(acc[t][q] + bv, 0.f);
        C[(size_t)r * BN + c] = f2bf_rne(v);
      }
    }
  }
}

// ---------------------------------------------------------------------------
// Fused SAGE out-GEMM + next-layer p-GEMM.
// Phase 1/2: C = relu(A1@W1^T + A2@W2^T + bias)  (A from global, W in LDS)
// Phase 3 (if P_out): P_out = relu(C@Wp^T + pBias). A is re-read from C: each
//   lane reads ONLY rows this block itself wrote; block-local store->load
//   visibility is guaranteed by __syncthreads() (same CU -> same XCD L2),
//   so NO device-scope fence is needed (threadfence on gfx950 flushes the
//   per-XCD L2 and serialized the whole grid in r15).
template <int TNT>  // BN = TNT*16
__global__ __launch_bounds__(256) void mfma_gemm_fused_kernel(
    const unsigned short* __restrict__ A1, const unsigned short* __restrict__ Wh1,
    const unsigned short* __restrict__ Wl1,
    const unsigned short* __restrict__ A2, const unsigned short* __restrict__ Wh2,
    const unsigned short* __restrict__ Wl2, int K,
    const float* __restrict__ bias, unsigned short* __restrict__ C,
    const unsigned short* __restrict__ pWh, const unsigned short* __restrict__ pWl,
    const float* __restrict__ pBias, unsigned short* __restrict__ P_out,
    int nrows) {
  constexpr int BN = TNT * 16;
  constexpr int WS = 136;
  __shared__ __align__(16) unsigned short Wh[BN][WS];
  __shared__ __align__(16) unsigned short Wl[BN][WS];

  const int tid = threadIdx.x;
  const int lane = tid & 63;
  const int wv = tid >> 6;
  const int lr = lane & 15;
  const int lg = lane >> 4;
  const int row0 = blockIdx.x * 64;
  const int gra = row0 + wv * 16 + lr;

  f32x4 acc[TNT];
#pragma unroll
  for (int t = 0; t < TNT; ++t) acc[t] = (f32x4)(0.f);

  for (int pass = 0; pass < 2; ++pass) {
    const unsigned short* A = pass ? A2 : A1;
    const unsigned short* Whp = pass ? Wh2 : Wh1;
    const unsigned short* Wlp = pass ? Wl2 : Wl1;

    if (pass) __syncthreads();
    {
      int tot8 = BN * K / 8;
      for (int i = tid; i < tot8; i += 256) {
        int e0 = i * 8;
        int col = e0 / K;
        int kk = e0 - col * K;
        *(uint4*)&Wh[col][kk] = *(const uint4*)(Whp + e0);
        *(uint4*)&Wl[col][kk] = *(const uint4*)(Wlp + e0);
      }
    }
    __syncthreads();

    for (int cb = 0; cb < K; cb += 32) {
      i32x4 a_h = (i32x4)(0);
      if (gra < nrows) a_h = *(const i32x4*)(A + (size_t)gra * K + cb + lg * 8);
#pragma unroll
      for (int t = 0; t < TNT; ++t) {
        i32x4 b_h = *(const i32x4*)&Wh[t * 16 + lr][cb + lg * 8];
        i32x4 b_l = *(const i32x4*)&Wl[t * 16 + lr][cb + lg * 8];
        mfma_b16(acc[t], a_h, b_h);
        mfma_b16(acc[t], a_h, b_l);
      }
    }
  }

  asm volatile("s_nop 7\n\ts_nop 7" ::);

#pragma unroll
  for (int t = 0; t < TNT; ++t) {
    int c = t * 16 + lr;
    float bv = bias[c];
#pragma unroll
    for (int q = 0; q < 4; ++q) {
      int r = row0 + wv * 16 + lg * 4 + q;
      if (r < nrows) {
        float v = fmaxf(acc[t][q] + bv, 0.f);
        C[(size_t)r * BN + c] = f2bf_rne(v);
      }
    }
  }

  if (P_out == nullptr) return;

  // ---- phase 3: p_next = relu(C @ Wp^T + pBias), K_p = BN ----
  __syncthreads();   // orders this block's C stores before its own C loads
  {
    int tot8 = BN * BN / 8;
    for (int i = tid; i < tot8; i += 256) {
      int e0 = i * 8;
      int col = e0 / BN;
      int kk = e0 - col * BN;
      *(uint4*)&Wh[col][kk] = *(const uint4*)(pWh + e0);
      *(uint4*)&Wl[col][kk] = *(const uint4*)(pWl + e0);
    }
  }
  __syncthreads();

#pragma unroll
  for (int t = 0; t < TNT; ++t) acc[t] = (f32x4)(0.f);

  for (int cb = 0; cb < BN; cb += 32) {
    i32x4 a_h = (i32x4)(0);
    if (gra < nrows) a_h = *(const i32x4*)(C + (size_t)gra * BN + cb + lg * 8);
#pragma unroll
    for (int t = 0; t < TNT; ++t) {
      i32x4 b_h = *(const i32x4*)&Wh[t * 16 + lr][cb + lg * 8];
      i32x4 b_l = *(const i32x4*)&Wl[t * 16 + lr][cb + lg * 8];
      mfma_b16(acc[t], a_h, b_h);
      mfma_b16(acc[t], a_h, b_l);
    }
  }

  asm volatile("s_nop 7\n\ts_nop 7" ::);

#pragma unroll
  for (int t = 0; t < TNT; ++t) {
    int c = t * 16 + lr;
    float bv = pBias[c];
#pragma unroll
    for (int q = 0; q < 4; ++q) {
      int r = row0 + wv * 16 + lg * 4 + q;
      if (r < nrows) {
        float v = fmaxf(acc[t][q] + bv, 0.f);
        P_out[(size_t)r * BN + c] = f2bf_rne(v);
      }
    }
  }
}

// ---------------------------------------------------------------------------
// z = H @ Wnp^T + bnp  (H: [n,64] bf16, Wnp: [16,64] f32) then LayerNorm(16)
__global__ __launch_bounds__(256) void nodepred_ln_kernel(
    const unsigned short* __restrict__ H, const float* __restrict__ Wnp,
    const float* __restrict__ bnp, const float* __restrict__ g,
    const float* __restrict__ lb, float* __restrict__ out, int nrows) {
  __shared__ float hs[16][64];
  int tid = threadIdx.x;
  int row0 = blockIdx.x * 16;
  {
    int r = tid >> 4;
    int c4 = (tid & 15) << 2;
    int gr = row0 + r;
    float4 v = make_float4(0.f, 0.f, 0.f, 0.f);
    if (gr < nrows) v = bf4_to_f4(*(const uint2*)(H + (size_t)gr * 64 + c4));
    *(float4*)&hs[r][c4] = v;
  }
  __syncthreads();
  int r = tid >> 4, j = tid & 15;
  float z = bnp[j];
  const float* wrow = Wnp + j * 64;
#pragma unroll 8
  for (int k = 0; k < 64; ++k) z += hs[r][k] * wrow[k];
  float s = z, s2 = z * z;
#pragma unroll
  for (int m = 1; m < 16; m <<= 1) {
    s += __shfl_xor(s, m, 16);
    s2 += __shfl_xor(s2, m, 16);
  }
  float mu = s * (1.f / 16.f);
  float var = s2 * (1.f / 16.f) - mu * mu;
  float o = (z - mu) * rsqrtf(var + EPS_LN) * g[j] + lb[j];
  int gr = row0 + r;
  if (gr < nrows) out[(size_t)gr * 16 + j] = o;
}

// ---------------------------------------------------------------------------
// out1[i] = f32(R_bf16[mn[i]]), out2[i] = X_f32[mn[i]]   (rows of 128)
__global__ __launch_bounds__(256) void gather_out_kernel(
    const int* __restrict__ mn, const unsigned short* __restrict__ R,
    const float* __restrict__ X,
    float* __restrict__ o1, float* __restrict__ o2, int nmask) {
  int gid = blockIdx.x * 256 + threadIdx.x;
  if (gid >= nmask * 32) return;
  int i = gid >> 5, c4 = (gid & 31) << 2;
  int r = mn[i];
  float4 rv = bf4_to_f4(*(const uint2*)(R + (size_t)r * 128 + c4));
  *(float4*)(o1 + (size_t)i * 128 + c4) = rv;
  *(float4*)(o2 + (size_t)i * 128 + c4) = *(const float4*)(X + (size_t)r * 128 + c4);
}

// ---------------------------------------------------------------------------
static void launch_fused(const unsigned short* A1, const unsigned short* Wh1,
                         const unsigned short* Wl1,
                         const unsigned short* A2, const unsigned short* Wh2,
                         const unsigned short* Wl2, int K,
                         const float* bias, unsigned short* C,
                         const unsigned short* pWh, const unsigned short* pWl,
                         const float* pBias, unsigned short* P_out,
                         int m, int nrows, hipStream_t s) {
  int blocks = (nrows + 63) / 64;
  switch (m) {
    case 128:
      mfma_gemm_fused_kernel<8><<<blocks, 256, 0, s>>>(A1, Wh1, Wl1, A2, Wh2, Wl2, K,
                                                       bias, C, pWh, pWl, pBias, P_out, nrows);
      break;
    case 96:
      mfma_gemm_fused_kernel<6><<<blocks, 256, 0, s>>>(A1, Wh1, Wl1, A2, Wh2, Wl2, K,
                                                       bias, C, pWh, pWl, pBias, P_out, nrows);
      break;
    case 64:
      mfma_gemm_fused_kernel<4><<<blocks, 256, 0, s>>>(A1, Wh1, Wl1, A2, Wh2, Wl2, K,
                                                       bias, C, pWh, pWl, pBias, P_out, nrows);
      break;
  }
}

extern "C" void kernel_launch(void* const* d_in, const int* in_sizes, int n_in,
                              void* d_out, int out_size, void* d_ws, size_t ws_size,
                              hipStream_t stream) {
  const float* x = (const float*)d_in[0];
  const int* src = (const int*)d_in[1];
  const int* dst = (const int*)d_in[2];
  const float* ew = (const float*)d_in[3];
  const int* mn = (const int*)d_in[4];
  const float* token = (const float*)d_in[5];

  const float* W[20];
  for (int i = 0; i < 20; ++i) W[i] = (const float*)d_in[6 + i];
  const float* W_e2d = (const float*)d_in[26];
  const float* Wnp = (const float*)d_in[27];
  const float* bnp = (const float*)d_in[28];
  const float* ln_g = (const float*)d_in[29];
  const float* ln_b = (const float*)d_in[30];

  const int Nn = in_sizes[0] / 128;   // 50000
  const int E = in_sizes[1];          // 600000
  const int nmask = in_sizes[4];      // 10000
  const int nb = (Nn + SCAN_CHUNK - 1) / SCAN_CHUNK;  // 49

  // workspace layout (bf16 activations)
  unsigned short* bufA = (unsigned short*)d_ws;            // N*128 bf16
  unsigned short* bufB = bufA + (size_t)Nn * 128;          // N*128 bf16
  unsigned short* pool16 = bufB + (size_t)Nn * 128;        // N*128 bf16
  unsigned short* neigh16 = pool16 + (size_t)Nn * 128;     // N*128 bf16
  int* deg = (int*)(neigh16 + (size_t)Nn * 128);           // N int
  int* cur = deg + Nn;                                     // N int
  int2* esw = (int2*)(cur + Nn);                           // E int2
  int* off = (int*)(esw + E);                              // N+1 int
  int* bsum = off + Nn + 1;                                // 64 int
  int* bbase = bsum + 64;                                  // 64 int
  float* WpP = (float*)(bbase + 64);                       // 64*64 f32
  float* WsP = WpP + 64 * 64;                              // 96*64 f32
  unsigned short* wplanes =
      (unsigned short*)(((uintptr_t)(WsP + 96 * 64) + 15) & ~(uintptr_t)15);

  // plane table
  const int msz[12] = {128 * 128, 96 * 128, 96 * 128, 96 * 96, 64 * 96, 64 * 96,
                       64 * 64,  96 * 64,  96 * 64,  96 * 96, 128 * 96, 128 * 96};
  const float* msrc[12] = {W[0], W[2], W[3], W[5], W[7], W[8],
                           WpP,  WsP,  W[13], W[15], W[17], W[18]};
  int mtot = 0;
  int moff[12];
  for (int i = 0; i < 12; ++i) { moff[i] = mtot; mtot += msz[i]; }
  unsigned short* wh_[12];
  unsigned short* wl_[12];
  for (int i = 0; i < 12; ++i) {
    wh_[i] = wplanes + moff[i];
    wl_[i] = wplanes + mtot + moff[i];
  }

  // ---- dispatch 1: zero deg+cur ----
  hipMemsetAsync(deg, 0, (size_t)Nn * 2 * sizeof(int), stream);

  // ---- dispatch 2: prep1 = {copy_bf16 | hist | WpP | WsP} ----
  Prep1Args p1;
  p1.x4 = (const float4*)x;
  p1.h_out = (uint2*)bufA;
  p1.n4 = Nn * 128 / 4;
  p1.cb_blocks = (p1.n4 + 255) / 256;
  p1.dst = dst;
  p1.deg = deg;
  p1.nE = E;
  p1.hist_blocks = (E + 255) / 256;
  p1.W10 = W[10]; p1.We2d = W_e2d; p1.WpP = WpP;
  p1.W12 = W[12]; p1.WsP = WsP;
  int p1_blocks = p1.cb_blocks + p1.hist_blocks + 16 + 24;
  prep1_kernel<<<p1_blocks, 256, 0, stream>>>(p1);

  // ---- dispatch 3: prep2 = {blocksum | mask_scatter | split_w} ----
  Prep2Args p2;
  p2.deg = deg; p2.bsum = bsum; p2.n = Nn; p2.nb = nb;
  p2.mn = mn; p2.token = token; p2.H = bufA; p2.nmask = nmask;
  p2.ms_blocks = (nmask * 32 + 255) / 256;
  for (int i = 0; i < 12; ++i) {
    p2.sw.src[i] = msrc[i];
    p2.sw.dh[i] = wh_[i];
    p2.sw.dl[i] = wl_[i];
    p2.sw.n[i] = msz[i];
  }
  p2.boff[0] = 0;
  for (int i = 0; i < 12; ++i) p2.boff[i + 1] = p2.boff[i] + (msz[i] / 4 + 255) / 256;
  int p2_blocks = p2.nb + p2.ms_blocks + p2.boff[12];
  prep2_kernel<<<p2_blocks, 256, 0, stream>>>(p2);

  // ---- CSR scan + scatter ----
  bscan_kernel<<<1, 64, 0, stream>>>(bsum, bbase, off + Nn, nb);
  chunkscan_kernel<<<nb, 256, 0, stream>>>(deg, bbase, off, Nn);
  scatter_kernel<<<(E + 255) / 256, 256, 0, stream>>>(src, dst, ew, off, cur, esw, E);

  int gblocks = (Nn + 63) / 64;

  // ---- enc0 p (standalone): pool = relu(h0 @ Wp0^T + b1), 128x128 ----
  mfma_gemm_kernel<8><<<gblocks, 256, 0, stream>>>(bufA, wh_[0], wl_[0], 128, W[1],
                                                   pool16, Nn);

  auto neigh = [&](int din) {
    int lanes = din >> 3;
    long long tot = (long long)Nn * lanes;
    int nblocks = (int)((tot + 255) / 256);
    neigh_csr_kernel<<<nblocks, 256, 0, stream>>>(pool16, off, esw, neigh16, din, lanes, Nn);
  };

  // ---- enc0: h1[96] = relu(h0@Ws+neigh@Wn+b) ; fused p_enc1 -> pool ----
  neigh(128);
  launch_fused(bufA, wh_[1], wl_[1], neigh16, wh_[2], wl_[2], 128, W[4], bufB,
               wh_[3], wl_[3], W[6], pool16, 96, Nn, stream);

  // ---- enc1: h2[64] ; fused p_dec0 (folded WpP) -> pool ----
  neigh(96);
  launch_fused(bufB, wh_[4], wl_[4], neigh16, wh_[5], wl_[5], 96, W[9], bufA,
               wh_[6], wl_[6], W[11], pool16, 64, Nn, stream);

  // node_pred + layernorm on h2 (before bufA is overwritten by dec1's out)
  float* out_r = (float*)d_out;
  float* out_x = out_r + (size_t)nmask * 128;
  float* out_ns = out_x + (size_t)nmask * 128;
  nodepred_ln_kernel<<<(Nn + 15) / 16, 256, 0, stream>>>(bufA, Wnp, bnp, ln_g, ln_b, out_ns, Nn);

  // ---- dec0: h3[96] = relu(h2@WsP+neigh@Wn+b) ; fused p_dec1 -> pool ----
  neigh(64);
  launch_fused(bufA, wh_[7], wl_[7], neigh16, wh_[8], wl_[8], 64, W[14], bufB,
               wh_[9], wl_[9], W[16], pool16, 96, Nn, stream);

  // ---- dec1: h4[128] (no fused p) ----
  neigh(96);
  launch_fused(bufB, wh_[10], wl_[10], neigh16, wh_[11], wl_[11], 96, W[19], bufA,
               nullptr, nullptr, nullptr, nullptr, 128, Nn, stream);

  // outputs 1 & 2
  gather_out_kernel<<<(nmask * 32 + 255) / 256, 256, 0, stream>>>(mn, bufA, x, out_r, out_x, nmask);
}

// Round 17
// 320.684 us; speedup vs baseline: 1.6741x; 1.0531x over previous
//
#include <hip/hip_runtime.h>

#define EPS_LN 1e-5f

typedef __attribute__((ext_vector_type(4))) float f32x4;
typedef __attribute__((ext_vector_type(4))) int i32x4;

// ---------------------------------------------------------------------------
// bf16 helpers
__device__ inline unsigned short f2bf_rne(float x) {
  unsigned int u = __float_as_uint(x);
  unsigned int r = u + 0x7fffu + ((u >> 16) & 1u);
  return (unsigned short)(r >> 16);
}

__device__ inline float4 bf4_to_f4(uint2 u) {
  float4 f;
  f.x = __uint_as_float(u.x << 16);
  f.y = __uint_as_float(u.x & 0xffff0000u);
  f.z = __uint_as_float(u.y << 16);
  f.w = __uint_as_float(u.y & 0xffff0000u);
  return f;
}

__device__ inline uint2 f4_to_bf4(float4 v) {
  uint2 o;
  o.x = (unsigned)f2bf_rne(v.x) | ((unsigned)f2bf_rne(v.y) << 16);
  o.y = (unsigned)f2bf_rne(v.z) | ((unsigned)f2bf_rne(v.w) << 16);
  return o;
}

__device__ inline void split_bf16(float x, unsigned short& hi, unsigned short& lo) {
  unsigned int bits = __float_as_uint(x);
  hi = (unsigned short)(bits >> 16);
  float hif = __uint_as_float((unsigned int)hi << 16);
  float res = x - hif;
  lo = (unsigned short)(__float_as_uint(res) >> 16);
}

__device__ inline void mfma_b16(f32x4& acc, i32x4 a, i32x4 b) {
  asm volatile("v_mfma_f32_16x16x32_bf16 %0, %1, %2, %0"
               : "+v"(acc)
               : "v"(a), "v"(b));
}

// ---------------------------------------------------------------------------
struct SplitWArgs {
  const float* src[12];
  unsigned short* dh[12];
  unsigned short* dl[12];
  int n[12];
};

// prep1: sections {copy_bf16 | hist | WpP=W10@We2d | WsP=W12@We2d}
struct Prep1Args {
  const float4* x4; uint2* h_out; int n4; int cb_blocks;
  const int* dst; int* deg; int nE; int hist_blocks;
  const float* W10; const float* We2d; float* WpP;
  const float* W12; float* WsP;
};

__global__ __launch_bounds__(256) void prep1_kernel(Prep1Args a) {
  int b = blockIdx.x;
  int tid = threadIdx.x;
  if (b < a.cb_blocks) {  // x f32 -> h bf16
    int i = b * 256 + tid;
    if (i < a.n4) a.h_out[i] = f4_to_bf4(a.x4[i]);
    return;
  }
  b -= a.cb_blocks;
  if (b < a.hist_blocks) {  // deg histogram
    int e = b * 256 + tid;
    if (e < a.nE) atomicAdd(a.deg + a.dst[e], 1);
    return;
  }
  b -= a.hist_blocks;
  if (b < 16) {  // WpP[64][64] = W10 @ We2d
    int idx = b * 256 + tid;
    if (idx < 64 * 64) {
      int o = idx >> 6, i = idx & 63;
      float s = 0.f;
      for (int k = 0; k < 64; ++k) s += a.W10[o * 64 + k] * a.We2d[k * 64 + i];
      a.WpP[idx] = s;
    }
    return;
  }
  b -= 16;
  {  // WsP[96][64] = W12 @ We2d
    int idx = b * 256 + tid;
    if (idx < 96 * 64) {
      int o = idx >> 6, i = idx & 63;
      float s = 0.f;
      for (int k = 0; k < 64; ++k) s += a.W12[o * 64 + k] * a.We2d[k * 64 + i];
      a.WsP[idx] = s;
    }
  }
}

// prep2: sections {blocksum | mask_scatter | split_w}
#define SCAN_CHUNK 1024

struct Prep2Args {
  const int* deg; int* bsum; int n; int nb;
  const int* mn; const float* token; unsigned short* H; int nmask; int ms_blocks;
  SplitWArgs sw;
  int boff[13];
};

__global__ __launch_bounds__(256) void prep2_kernel(Prep2Args a) {
  __shared__ int red[256];
  int b = blockIdx.x;
  int tid = threadIdx.x;
  if (b < a.nb) {  // per-chunk degree sums
    int base = b * SCAN_CHUNK;
    int s = 0;
#pragma unroll
    for (int t = 0; t < SCAN_CHUNK / 256; ++t) {
      int g = base + tid + t * 256;
      if (g < a.n) s += a.deg[g];
    }
    red[tid] = s;
    __syncthreads();
    for (int ofs = 128; ofs > 0; ofs >>= 1) {
      if (tid < ofs) red[tid] += red[tid + ofs];
      __syncthreads();
    }
    if (tid == 0) a.bsum[b] = red[0];
    return;
  }
  b -= a.nb;
  if (b < a.ms_blocks) {  // mask token scatter into bf16 H
    int gid = b * 256 + tid;
    if (gid >= a.nmask * 32) return;
    int i = gid >> 5;
    int c4 = (gid & 31) << 2;
    int r = a.mn[i];
    float4 t = *(const float4*)(a.token + c4);
    *(uint2*)(a.H + (size_t)r * 128 + c4) = f4_to_bf4(t);
    return;
  }
  b -= a.ms_blocks;
  {  // split weights into hi/lo planes
    int m = 0;
    while (m < 11 && b >= a.boff[m + 1]) ++m;
    int i = ((b - a.boff[m]) * 256 + tid) * 4;
    if (i >= a.sw.n[m]) return;
    float4 v = *(const float4*)(a.sw.src[m] + i);
    unsigned short h[4], l[4];
    split_bf16(v.x, h[0], l[0]);
    split_bf16(v.y, h[1], l[1]);
    split_bf16(v.z, h[2], l[2]);
    split_bf16(v.w, h[3], l[3]);
    *(uint2*)(a.sw.dh[m] + i) = make_uint2((unsigned)h[0] | ((unsigned)h[1] << 16),
                                           (unsigned)h[2] | ((unsigned)h[3] << 16));
    *(uint2*)(a.sw.dl[m] + i) = make_uint2((unsigned)l[0] | ((unsigned)l[1] << 16),
                                           (unsigned)l[2] | ((unsigned)l[3] << 16));
  }
}

// ---------------------------------------------------------------------------
// chunkscan with inlined bsum-scan (each block redundantly scans <=64 sums)
__global__ __launch_bounds__(256) void chunkscan_kernel(const int* __restrict__ deg,
                                                        const int* __restrict__ bsum,
                                                        int* __restrict__ off,
                                                        int n, int nb) {
  __shared__ int part[256];
  __shared__ int basesh;
  int tid = threadIdx.x;
  // wave 0: exclusive-scan bsum, pick this block's base
  if (tid < 64) {
    int v = (tid < nb) ? bsum[tid] : 0;
    int incl = v;
#pragma unroll
    for (int ofs = 1; ofs < 64; ofs <<= 1) {
      int u = __shfl_up(incl, ofs, 64);
      if (tid >= ofs) incl += u;
    }
    if (tid == (int)blockIdx.x) basesh = incl - v;
    if (blockIdx.x == 0 && tid == nb - 1) off[n] = incl;
  }
  int base = blockIdx.x * SCAN_CHUNK;
  int g0 = base + tid * 4;
  int loc[4];
  int s = 0;
#pragma unroll
  for (int j = 0; j < 4; ++j) {
    int g = g0 + j;
    int d = (g < n) ? deg[g] : 0;
    loc[j] = s;
    s += d;
  }
  part[tid] = s;
  __syncthreads();
  for (int ofs = 1; ofs < 256; ofs <<= 1) {
    int v = 0;
    if (tid >= ofs) v = part[tid - ofs];
    __syncthreads();
    if (tid >= ofs) part[tid] += v;
    __syncthreads();
  }
  int pre = (tid == 0) ? 0 : part[tid - 1];
  int b = basesh + pre;
#pragma unroll
  for (int j = 0; j < 4; ++j) {
    int g = g0 + j;
    if (g < n) off[g] = b + loc[j];
  }
}

// ---------------------------------------------------------------------------
// ComboA: sections {scatter | enc0 p-GEMM (TNT=8, K=128)}
struct ComboAArgs {
  // scatter
  const int* src; const int* dst; const float* ew;
  const int* off; int* cur; int2* esw; int nE; int sc_blocks;
  // gemm
  const unsigned short* A1; const unsigned short* Wh1; const unsigned short* Wl1;
  const float* bias; unsigned short* C; int nrows;
};

__global__ __launch_bounds__(256) void comboA_kernel(ComboAArgs a) {
  __shared__ __align__(16) unsigned short Wh[128][136];
  __shared__ __align__(16) unsigned short Wl[128][136];
  int b = blockIdx.x;
  int tid = threadIdx.x;
  if (b < a.sc_blocks) {  // scatter
    int e = b * 256 + tid;
    if (e >= a.nE) return;
    int d = a.dst[e];
    int pos = a.off[d] + atomicAdd(a.cur + d, 1);
    a.esw[pos] = make_int2(a.src[e], __float_as_int(a.ew[e]));
    return;
  }
  b -= a.sc_blocks;
  // enc0 p GEMM: pool = relu(h0 @ Wp0^T + b), 128x128
  constexpr int K = 128;
  const int lane = tid & 63;
  const int wv = tid >> 6;
  const int lr = lane & 15;
  const int lg = lane >> 4;
  const int row0 = b * 64;
  const int gra = row0 + wv * 16 + lr;

  f32x4 acc[8];
#pragma unroll
  for (int t = 0; t < 8; ++t) acc[t] = (f32x4)(0.f);

  {
    int tot8 = 128 * K / 8;
    for (int i = tid; i < tot8; i += 256) {
      int e0 = i * 8;
      int col = e0 / K;
      int kk = e0 - col * K;
      *(uint4*)&Wh[col][kk] = *(const uint4*)(a.Wh1 + e0);
      *(uint4*)&Wl[col][kk] = *(const uint4*)(a.Wl1 + e0);
    }
  }
  __syncthreads();

  for (int cb = 0; cb < K; cb += 32) {
    i32x4 a_h = (i32x4)(0);
    if (gra < a.nrows) a_h = *(const i32x4*)(a.A1 + (size_t)gra * K + cb + lg * 8);
#pragma unroll
    for (int t = 0; t < 8; ++t) {
      i32x4 b_h = *(const i32x4*)&Wh[t * 16 + lr][cb + lg * 8];
      i32x4 b_l = *(const i32x4*)&Wl[t * 16 + lr][cb + lg * 8];
      mfma_b16(acc[t], a_h, b_h);
      mfma_b16(acc[t], a_h, b_l);
    }
  }

  asm volatile("s_nop 7\n\ts_nop 7" ::);

#pragma unroll
  for (int t = 0; t < 8; ++t) {
    int c = t * 16 + lr;
    float bv = a.bias[c];
#pragma unroll
    for (int q = 0; q < 4; ++q) {
      int r = row0 + wv * 16 + lg * 4 + q;
      if (r < a.nrows) {
        float v = fmaxf(acc[t][q] + bv, 0.f);
        a.C[(size_t)r * 128 + c] = f2bf_rne(v);
      }
    }
  }
}

// ---------------------------------------------------------------------------
// neigh body (device): per-node segment max, din/8 lanes per node, uint4 loads
__device__ inline void neigh_body(int gid, const unsigned short* P, const int* off,
                                  const int2* esw, unsigned short* neigh,
                                  int din, int lanes, int nN) {
  int v = gid / lanes;
  int c = (gid - v * lanes) << 3;
  if (v >= nN) return;
  int jlo = off[v], jhi = off[v + 1];
  float m[8];
#pragma unroll
  for (int t = 0; t < 8; ++t) m[t] = 0.f;
  float n1[8], n2[8], n3[8];
#pragma unroll
  for (int t = 0; t < 8; ++t) { n1[t] = 0.f; n2[t] = 0.f; n3[t] = 0.f; }
  int j = jlo;
  for (; j + 4 <= jhi; j += 4) {
    int2 e0 = esw[j], e1 = esw[j + 1], e2 = esw[j + 2], e3 = esw[j + 3];
    uint4 q0 = *(const uint4*)(P + (size_t)e0.x * din + c);
    uint4 q1 = *(const uint4*)(P + (size_t)e1.x * din + c);
    uint4 q2 = *(const uint4*)(P + (size_t)e2.x * din + c);
    uint4 q3 = *(const uint4*)(P + (size_t)e3.x * din + c);
    float w0 = __int_as_float(e0.y), w1 = __int_as_float(e1.y);
    float w2 = __int_as_float(e2.y), w3 = __int_as_float(e3.y);
    float4 a0 = bf4_to_f4(make_uint2(q0.x, q0.y)), b0 = bf4_to_f4(make_uint2(q0.z, q0.w));
    float4 a1 = bf4_to_f4(make_uint2(q1.x, q1.y)), b1 = bf4_to_f4(make_uint2(q1.z, q1.w));
    float4 a2 = bf4_to_f4(make_uint2(q2.x, q2.y)), b2 = bf4_to_f4(make_uint2(q2.z, q2.w));
    float4 a3 = bf4_to_f4(make_uint2(q3.x, q3.y)), b3 = bf4_to_f4(make_uint2(q3.z, q3.w));
    m[0] = fmaxf(m[0], a0.x * w0); m[1] = fmaxf(m[1], a0.y * w0);
    m[2] = fmaxf(m[2], a0.z * w0); m[3] = fmaxf(m[3], a0.w * w0);
    m[4] = fmaxf(m[4], b0.x * w0); m[5] = fmaxf(m[5], b0.y * w0);
    m[6] = fmaxf(m[6], b0.z * w0); m[7] = fmaxf(m[7], b0.w * w0);
    n1[0] = fmaxf(n1[0], a1.x * w1); n1[1] = fmaxf(n1[1], a1.y * w1);
    n1[2] = fmaxf(n1[2], a1.z * w1); n1[3] = fmaxf(n1[3], a1.w * w1);
    n1[4] = fmaxf(n1[4], b1.x * w1); n1[5] = fmaxf(n1[5], b1.y * w1);
    n1[6] = fmaxf(n1[6], b1.z * w1); n1[7] = fmaxf(n1[7], b1.w * w1);
    n2[0] = fmaxf(n2[0], a2.x * w2); n2[1] = fmaxf(n2[1], a2.y * w2);
    n2[2] = fmaxf(n2[2], a2.z * w2); n2[3] = fmaxf(n2[3], a2.w * w2);
    n2[4] = fmaxf(n2[4], b2.x * w2); n2[5] = fmaxf(n2[5], b2.y * w2);
    n2[6] = fmaxf(n2[6], b2.z * w2); n2[7] = fmaxf(n2[7], b2.w * w2);
    n3[0] = fmaxf(n3[0], a3.x * w3); n3[1] = fmaxf(n3[1], a3.y * w3);
    n3[2] = fmaxf(n3[2], a3.z * w3); n3[3] = fmaxf(n3[3], a3.w * w3);
    n3[4] = fmaxf(n3[4], b3.x * w3); n3[5] = fmaxf(n3[5], b3.y * w3);
    n3[6] = fmaxf(n3[6], b3.z * w3); n3[7] = fmaxf(n3[7], b3.w * w3);
  }
  for (; j < jhi; ++j) {
    int2 e = esw[j];
    float w = __int_as_float(e.y);
    uint4 q = *(const uint4*)(P + (size_t)e.x * din + c);
    float4 a = bf4_to_f4(make_uint2(q.x, q.y)), b = bf4_to_f4(make_uint2(q.z, q.w));
    m[0] = fmaxf(m[0], a.x * w); m[1] = fmaxf(m[1], a.y * w);
    m[2] = fmaxf(m[2], a.z * w); m[3] = fmaxf(m[3], a.w * w);
    m[4] = fmaxf(m[4], b.x * w); m[5] = fmaxf(m[5], b.y * w);
    m[6] = fmaxf(m[6], b.z * w); m[7] = fmaxf(m[7], b.w * w);
  }
#pragma unroll
  for (int t = 0; t < 8; ++t) m[t] = fmaxf(fmaxf(m[t], n1[t]), fmaxf(n2[t], n3[t]));
  uint2 o0 = f4_to_bf4(make_float4(m[0], m[1], m[2], m[3]));
  uint2 o1 = f4_to_bf4(make_float4(m[4], m[5], m[6], m[7]));
  *(uint4*)(neigh + (size_t)v * din + c) = make_uint4(o0.x, o0.y, o1.x, o1.y);
}

__global__ __launch_bounds__(256) void neigh_csr_kernel(
    const unsigned short* __restrict__ P, const int* __restrict__ off,
    const int2* __restrict__ esw,
    unsigned short* __restrict__ neigh, int din, int lanes, int nN) {
  int gid = blockIdx.x * 256 + threadIdx.x;
  neigh_body(gid, P, off, esw, neigh, din, lanes, nN);
}

// ---------------------------------------------------------------------------
// ComboB: sections {neigh(din=64) | nodepred_ln}
struct ComboBArgs {
  const unsigned short* P; const int* off; const int2* esw;
  unsigned short* neigh; int nN; int ng_blocks;
  const unsigned short* H; const float* Wnp; const float* bnp;
  const float* g; const float* lb; float* out;
};

__global__ __launch_bounds__(256) void comboB_kernel(ComboBArgs a) {
  __shared__ float hs[16][64];
  int b = blockIdx.x;
  int tid = threadIdx.x;
  if (b < a.ng_blocks) {  // neigh din=64 (lanes=8)
    neigh_body(b * 256 + tid, a.P, a.off, a.esw, a.neigh, 64, 8, a.nN);
    return;
  }
  b -= a.ng_blocks;
  // nodepred + layernorm
  int row0 = b * 16;
  {
    int r = tid >> 4;
    int c4 = (tid & 15) << 2;
    int gr = row0 + r;
    float4 v = make_float4(0.f, 0.f, 0.f, 0.f);
    if (gr < a.nN) v = bf4_to_f4(*(const uint2*)(a.H + (size_t)gr * 64 + c4));
    *(float4*)&hs[r][c4] = v;
  }
  __syncthreads();
  int r = tid >> 4, j = tid & 15;
  float z = a.bnp[j];
  const float* wrow = a.Wnp + j * 64;
#pragma unroll 8
  for (int k = 0; k < 64; ++k) z += hs[r][k] * wrow[k];
  float s = z, s2 = z * z;
#pragma unroll
  for (int m = 1; m < 16; m <<= 1) {
    s += __shfl_xor(s, m, 16);
    s2 += __shfl_xor(s2, m, 16);
  }
  float mu = s * (1.f / 16.f);
  float var = s2 * (1.f / 16.f) - mu * mu;
  float o = (z - mu) * rsqrtf(var + EPS_LN) * a.g[j] + a.lb[j];
  int gr = row0 + r;
  if (gr < a.nN) a.out[(size_t)gr * 16 + j] = o;
}

// ---------------------------------------------------------------------------
// Fused SAGE out-GEMM + next-layer p-GEMM (block-local phase 3, NO threadfence)
template <int TNT>  // BN = TNT*16
__global__ __launch_bounds__(256) void mfma_gemm_fused_kernel(
    const unsigned short* __restrict__ A1, const unsigned short* __restrict__ Wh1,
    const unsigned short* __restrict__ Wl1,
    const unsigned short* __restrict__ A2, const unsigned short* __restrict__ Wh2,
    const unsigned short* __restrict__ Wl2, int K,
    const float* __restrict__ bias, unsigned short* __restrict__ C,
    const unsigned short* __restrict__ pWh, const unsigned short* __restrict__ pWl,
    const float* __restrict__ pBias, unsigned short* __restrict__ P_out,
    int nrows) {
  constexpr int BN = TNT * 16;
  constexpr int WS = 136;
  __shared__ __align__(16) unsigned short Wh[BN][WS];
  __shared__ __align__(16) unsigned short Wl[BN][WS];

  const int tid = threadIdx.x;
  const int lane = tid & 63;
  const int wv = tid >> 6;
  const int lr = lane & 15;
  const int lg = lane >> 4;
  const int row0 = blockIdx.x * 64;
  const int gra = row0 + wv * 16 + lr;

  f32x4 acc[TNT];
#pragma unroll
  for (int t = 0; t < TNT; ++t) acc[t] = (f32x4)(0.f);

  for (int pass = 0; pass < 2; ++pass) {
    const unsigned short* A = pass ? A2 : A1;
    const unsigned short* Whp = pass ? Wh2 : Wh1;
    const unsigned short* Wlp = pass ? Wl2 : Wl1;

    if (pass) __syncthreads();
    {
      int tot8 = BN * K / 8;
      for (int i = tid; i < tot8; i += 256) {
        int e0 = i * 8;
        int col = e0 / K;
        int kk = e0 - col * K;
        *(uint4*)&Wh[col][kk] = *(const uint4*)(Whp + e0);
        *(uint4*)&Wl[col][kk] = *(const uint4*)(Wlp + e0);
      }
    }
    __syncthreads();

    for (int cb = 0; cb < K; cb += 32) {
      i32x4 a_h = (i32x4)(0);
      if (gra < nrows) a_h = *(const i32x4*)(A + (size_t)gra * K + cb + lg * 8);
#pragma unroll
      for (int t = 0; t < TNT; ++t) {
        i32x4 b_h = *(const i32x4*)&Wh[t * 16 + lr][cb + lg * 8];
        i32x4 b_l = *(const i32x4*)&Wl[t * 16 + lr][cb + lg * 8];
        mfma_b16(acc[t], a_h, b_h);
        mfma_b16(acc[t], a_h, b_l);
      }
    }
  }

  asm volatile("s_nop 7\n\ts_nop 7" ::);

#pragma unroll
  for (int t = 0; t < TNT; ++t) {
    int c = t * 16 + lr;
    float bv = bias[c];
#pragma unroll
    for (int q = 0; q < 4; ++q) {
      int r = row0 + wv * 16 + lg * 4 + q;
      if (r < nrows) {
        float v = fmaxf(acc[t][q] + bv, 0.f);
        C[(size_t)r * BN + c] = f2bf_rne(v);
      }
    }
  }

  if (P_out == nullptr) return;

  // phase 3: p_next = relu(C @ Wp^T + pBias); block-local C rows only
  __syncthreads();
  {
    int tot8 = BN * BN / 8;
    for (int i = tid; i < tot8; i += 256) {
      int e0 = i * 8;
      int col = e0 / BN;
      int kk = e0 - col * BN;
      *(uint4*)&Wh[col][kk] = *(const uint4*)(pWh + e0);
      *(uint4*)&Wl[col][kk] = *(const uint4*)(pWl + e0);
    }
  }
  __syncthreads();

#pragma unroll
  for (int t = 0; t < TNT; ++t) acc[t] = (f32x4)(0.f);

  for (int cb = 0; cb < BN; cb += 32) {
    i32x4 a_h = (i32x4)(0);
    if (gra < nrows) a_h = *(const i32x4*)(C + (size_t)gra * BN + cb + lg * 8);
#pragma unroll
    for (int t = 0; t < TNT; ++t) {
      i32x4 b_h = *(const i32x4*)&Wh[t * 16 + lr][cb + lg * 8];
      i32x4 b_l = *(const i32x4*)&Wl[t * 16 + lr][cb + lg * 8];
      mfma_b16(acc[t], a_h, b_h);
      mfma_b16(acc[t], a_h, b_l);
    }
  }

  asm volatile("s_nop 7\n\ts_nop 7" ::);

#pragma unroll
  for (int t = 0; t < TNT; ++t) {
    int c = t * 16 + lr;
    float bv = pBias[c];
#pragma unroll
    for (int q = 0; q < 4; ++q) {
      int r = row0 + wv * 16 + lg * 4 + q;
      if (r < nrows) {
        float v = fmaxf(acc[t][q] + bv, 0.f);
        P_out[(size_t)r * BN + c] = f2bf_rne(v);
      }
    }
  }
}

// ---------------------------------------------------------------------------
// out1[i] = f32(R_bf16[mn[i]]), out2[i] = X_f32[mn[i]]
__global__ __launch_bounds__(256) void gather_out_kernel(
    const int* __restrict__ mn, const unsigned short* __restrict__ R,
    const float* __restrict__ X,
    float* __restrict__ o1, float* __restrict__ o2, int nmask) {
  int gid = blockIdx.x * 256 + threadIdx.x;
  if (gid >= nmask * 32) return;
  int i = gid >> 5, c4 = (gid & 31) << 2;
  int r = mn[i];
  float4 rv = bf4_to_f4(*(const uint2*)(R + (size_t)r * 128 + c4));
  *(float4*)(o1 + (size_t)i * 128 + c4) = rv;
  *(float4*)(o2 + (size_t)i * 128 + c4) = *(const float4*)(X + (size_t)r * 128 + c4);
}

// ---------------------------------------------------------------------------
static void launch_fused(const unsigned short* A1, const unsigned short* Wh1,
                         const unsigned short* Wl1,
                         const unsigned short* A2, const unsigned short* Wh2,
                         const unsigned short* Wl2, int K,
                         const float* bias, unsigned short* C,
                         const unsigned short* pWh, const unsigned short* pWl,
                         const float* pBias, unsigned short* P_out,
                         int m, int nrows, hipStream_t s) {
  int blocks = (nrows + 63) / 64;
  switch (m) {
    case 128:
      mfma_gemm_fused_kernel<8><<<blocks, 256, 0, s>>>(A1, Wh1, Wl1, A2, Wh2, Wl2, K,
                                                       bias, C, pWh, pWl, pBias, P_out, nrows);
      break;
    case 96:
      mfma_gemm_fused_kernel<6><<<blocks, 256, 0, s>>>(A1, Wh1, Wl1, A2, Wh2, Wl2, K,
                                                       bias, C, pWh, pWl, pBias, P_out, nrows);
      break;
    case 64:
      mfma_gemm_fused_kernel<4><<<blocks, 256, 0, s>>>(A1, Wh1, Wl1, A2, Wh2, Wl2, K,
                                                       bias, C, pWh, pWl, pBias, P_out, nrows);
      break;
  }
}

extern "C" void kernel_launch(void* const* d_in, const int* in_sizes, int n_in,
                              void* d_out, int out_size, void* d_ws, size_t ws_size,
                              hipStream_t stream) {
  const float* x = (const float*)d_in[0];
  const int* src = (const int*)d_in[1];
  const int* dst = (const int*)d_in[2];
  const float* ew = (const float*)d_in[3];
  const int* mn = (const int*)d_in[4];
  const float* token = (const float*)d_in[5];

  const float* W[20];
  for (int i = 0; i < 20; ++i) W[i] = (const float*)d_in[6 + i];
  const float* W_e2d = (const float*)d_in[26];
  const float* Wnp = (const float*)d_in[27];
  const float* bnp = (const float*)d_in[28];
  const float* ln_g = (const float*)d_in[29];
  const float* ln_b = (const float*)d_in[30];

  const int Nn = in_sizes[0] / 128;   // 50000
  const int E = in_sizes[1];          // 600000
  const int nmask = in_sizes[4];      // 10000
  const int nb = (Nn + SCAN_CHUNK - 1) / SCAN_CHUNK;  // 49

  // workspace layout (bf16 activations)
  unsigned short* bufA = (unsigned short*)d_ws;            // N*128 bf16
  unsigned short* bufB = bufA + (size_t)Nn * 128;          // N*128 bf16
  unsigned short* pool16 = bufB + (size_t)Nn * 128;        // N*128 bf16
  unsigned short* neigh16 = pool16 + (size_t)Nn * 128;     // N*128 bf16
  int* deg = (int*)(neigh16 + (size_t)Nn * 128);           // N int
  int* cur = deg + Nn;                                     // N int
  int2* esw = (int2*)(cur + Nn);                           // E int2
  int* off = (int*)(esw + E);                              // N+1 int
  int* bsum = off + Nn + 1;                                // 64 int
  float* WpP = (float*)(bsum + 64);                        // 64*64 f32
  float* WsP = WpP + 64 * 64;                              // 96*64 f32
  unsigned short* wplanes =
      (unsigned short*)(((uintptr_t)(WsP + 96 * 64) + 15) & ~(uintptr_t)15);

  // plane table
  const int msz[12] = {128 * 128, 96 * 128, 96 * 128, 96 * 96, 64 * 96, 64 * 96,
                       64 * 64,  96 * 64,  96 * 64,  96 * 96, 128 * 96, 128 * 96};
  const float* msrc[12] = {W[0], W[2], W[3], W[5], W[7], W[8],
                           WpP,  WsP,  W[13], W[15], W[17], W[18]};
  int mtot = 0;
  int moff[12];
  for (int i = 0; i < 12; ++i) { moff[i] = mtot; mtot += msz[i]; }
  unsigned short* wh_[12];
  unsigned short* wl_[12];
  for (int i = 0; i < 12; ++i) {
    wh_[i] = wplanes + moff[i];
    wl_[i] = wplanes + mtot + moff[i];
  }

  // ---- dispatch 1: zero deg+cur ----
  hipMemsetAsync(deg, 0, (size_t)Nn * 2 * sizeof(int), stream);

  // ---- dispatch 2: prep1 ----
  Prep1Args p1;
  p1.x4 = (const float4*)x;
  p1.h_out = (uint2*)bufA;
  p1.n4 = Nn * 128 / 4;
  p1.cb_blocks = (p1.n4 + 255) / 256;
  p1.dst = dst;
  p1.deg = deg;
  p1.nE = E;
  p1.hist_blocks = (E + 255) / 256;
  p1.W10 = W[10]; p1.We2d = W_e2d; p1.WpP = WpP;
  p1.W12 = W[12]; p1.WsP = WsP;
  int p1_blocks = p1.cb_blocks + p1.hist_blocks + 16 + 24;
  prep1_kernel<<<p1_blocks, 256, 0, stream>>>(p1);

  // ---- dispatch 3: prep2 ----
  Prep2Args p2;
  p2.deg = deg; p2.bsum = bsum; p2.n = Nn; p2.nb = nb;
  p2.mn = mn; p2.token = token; p2.H = bufA; p2.nmask = nmask;
  p2.ms_blocks = (nmask * 32 + 255) / 256;
  for (int i = 0; i < 12; ++i) {
    p2.sw.src[i] = msrc[i];
    p2.sw.dh[i] = wh_[i];
    p2.sw.dl[i] = wl_[i];
    p2.sw.n[i] = msz[i];
  }
  p2.boff[0] = 0;
  for (int i = 0; i < 12; ++i) p2.boff[i + 1] = p2.boff[i] + (msz[i] / 4 + 255) / 256;
  int p2_blocks = p2.nb + p2.ms_blocks + p2.boff[12];
  prep2_kernel<<<p2_blocks, 256, 0, stream>>>(p2);

  // ---- dispatch 4: chunkscan (inlined bsum-scan) ----
  chunkscan_kernel<<<nb, 256, 0, stream>>>(deg, bsum, off, Nn, nb);

  // ---- dispatch 5: comboA = scatter || enc0 p-GEMM ----
  ComboAArgs ca;
  ca.src = src; ca.dst = dst; ca.ew = ew;
  ca.off = off; ca.cur = cur; ca.esw = esw; ca.nE = E;
  ca.sc_blocks = (E + 255) / 256;
  ca.A1 = bufA; ca.Wh1 = wh_[0]; ca.Wl1 = wl_[0];
  ca.bias = W[1]; ca.C = pool16; ca.nrows = Nn;
  int gblocks = (Nn + 63) / 64;
  comboA_kernel<<<ca.sc_blocks + gblocks, 256, 0, stream>>>(ca);

  auto neigh = [&](int din) {
    int lanes = din >> 3;
    long long tot = (long long)Nn * lanes;
    int nblocks = (int)((tot + 255) / 256);
    neigh_csr_kernel<<<nblocks, 256, 0, stream>>>(pool16, off, esw, neigh16, din, lanes, Nn);
  };

  // ---- enc0: h1[96]; fused p_enc1 -> pool ----
  neigh(128);
  launch_fused(bufA, wh_[1], wl_[1], neigh16, wh_[2], wl_[2], 128, W[4], bufB,
               wh_[3], wl_[3], W[6], pool16, 96, Nn, stream);

  // ---- enc1: h2[64]; fused p_dec0 (folded WpP) -> pool ----
  neigh(96);
  launch_fused(bufB, wh_[4], wl_[4], neigh16, wh_[5], wl_[5], 96, W[9], bufA,
               wh_[6], wl_[6], W[11], pool16, 64, Nn, stream);

  float* out_r = (float*)d_out;
  float* out_x = out_r + (size_t)nmask * 128;
  float* out_ns = out_x + (size_t)nmask * 128;

  // ---- comboB = neigh(64) || nodepred_ln(h2) ----
  ComboBArgs cb;
  cb.P = pool16; cb.off = off; cb.esw = esw; cb.neigh = neigh16; cb.nN = Nn;
  cb.ng_blocks = (Nn * 8 + 255) / 256;
  cb.H = bufA; cb.Wnp = Wnp; cb.bnp = bnp; cb.g = ln_g; cb.lb = ln_b; cb.out = out_ns;
  int np_blocks = (Nn + 15) / 16;
  comboB_kernel<<<cb.ng_blocks + np_blocks, 256, 0, stream>>>(cb);

  // ---- dec0: h3[96]; fused p_dec1 -> pool ----
  launch_fused(bufA, wh_[7], wl_[7], neigh16, wh_[8], wl_[8], 64, W[14], bufB,
               wh_[9], wl_[9], W[16], pool16, 96, Nn, stream);

  // ---- dec1: h4[128] (no fused p) ----
  neigh(96);
  launch_fused(bufB, wh_[10], wl_[10], neigh16, wh_[11], wl_[11], 96, W[19], bufA,
               nullptr, nullptr, nullptr, nullptr, 128, Nn, stream);

  // outputs 1 & 2
  gather_out_kernel<<<(nmask * 32 + 255) / 256, 256, 0, stream>>>(mn, bufA, x, out_r, out_x, nmask);
}

// Round 18
// 313.351 us; speedup vs baseline: 1.7133x; 1.0234x over previous
//
#include <hip/hip_runtime.h>

#define EPS_LN 1e-5f

typedef __attribute__((ext_vector_type(4))) float f32x4;
typedef __attribute__((ext_vector_type(4))) int i32x4;

// ---------------------------------------------------------------------------
// bf16 helpers
__device__ inline unsigned short f2bf_rne(float x) {
  unsigned int u = __float_as_uint(x);
  unsigned int r = u + 0x7fffu + ((u >> 16) & 1u);
  return (unsigned short)(r >> 16);
}

__device__ inline float4 bf4_to_f4(uint2 u) {
  float4 f;
  f.x = __uint_as_float(u.x << 16);
  f.y = __uint_as_float(u.x & 0xffff0000u);
  f.z = __uint_as_float(u.y << 16);
  f.w = __uint_as_float(u.y & 0xffff0000u);
  return f;
}

__device__ inline uint2 f4_to_bf4(float4 v) {
  uint2 o;
  o.x = (unsigned)f2bf_rne(v.x) | ((unsigned)f2bf_rne(v.y) << 16);
  o.y = (unsigned)f2bf_rne(v.z) | ((unsigned)f2bf_rne(v.w) << 16);
  return o;
}

__device__ inline void split_bf16(float x, unsigned short& hi, unsigned short& lo) {
  unsigned int bits = __float_as_uint(x);
  hi = (unsigned short)(bits >> 16);
  float hif = __uint_as_float((unsigned int)hi << 16);
  float res = x - hif;
  lo = (unsigned short)(__float_as_uint(res) >> 16);
}

__device__ inline void mfma_b16(f32x4& acc, i32x4 a, i32x4 b) {
  asm volatile("v_mfma_f32_16x16x32_bf16 %0, %1, %2, %0"
               : "+v"(acc)
               : "v"(a), "v"(b));
}

// ---------------------------------------------------------------------------
struct SplitWArgs {
  const float* src[12];
  unsigned short* dh[12];
  unsigned short* dl[12];
  int n[12];
};

// prep1: sections {copy_bf16 | hist | WpP=W10@We2d | WsP=W12@We2d}
struct Prep1Args {
  const float4* x4; uint2* h_out; int n4; int cb_blocks;
  const int* dst; int* deg; int nE; int hist_blocks;
  const float* W10; const float* We2d; float* WpP;
  const float* W12; float* WsP;
};

__global__ __launch_bounds__(256) void prep1_kernel(Prep1Args a) {
  int b = blockIdx.x;
  int tid = threadIdx.x;
  if (b < a.cb_blocks) {  // x f32 -> h bf16
    int i = b * 256 + tid;
    if (i < a.n4) a.h_out[i] = f4_to_bf4(a.x4[i]);
    return;
  }
  b -= a.cb_blocks;
  if (b < a.hist_blocks) {  // deg histogram
    int e = b * 256 + tid;
    if (e < a.nE) atomicAdd(a.deg + a.dst[e], 1);
    return;
  }
  b -= a.hist_blocks;
  if (b < 16) {  // WpP[64][64] = W10 @ We2d
    int idx = b * 256 + tid;
    if (idx < 64 * 64) {
      int o = idx >> 6, i = idx & 63;
      float s = 0.f;
      for (int k = 0; k < 64; ++k) s += a.W10[o * 64 + k] * a.We2d[k * 64 + i];
      a.WpP[idx] = s;
    }
    return;
  }
  b -= 16;
  {  // WsP[96][64] = W12 @ We2d
    int idx = b * 256 + tid;
    if (idx < 96 * 64) {
      int o = idx >> 6, i = idx & 63;
      float s = 0.f;
      for (int k = 0; k < 64; ++k) s += a.W12[o * 64 + k] * a.We2d[k * 64 + i];
      a.WsP[idx] = s;
    }
  }
}

// prep2: sections {blocksum | mask_scatter | split_w}
#define SCAN_CHUNK 1024

struct Prep2Args {
  const int* deg; int* bsum; int n; int nb;
  const int* mn; const float* token; unsigned short* H; int nmask; int ms_blocks;
  SplitWArgs sw;
  int boff[13];
};

__global__ __launch_bounds__(256) void prep2_kernel(Prep2Args a) {
  __shared__ int red[256];
  int b = blockIdx.x;
  int tid = threadIdx.x;
  if (b < a.nb) {  // per-chunk degree sums
    int base = b * SCAN_CHUNK;
    int s = 0;
#pragma unroll
    for (int t = 0; t < SCAN_CHUNK / 256; ++t) {
      int g = base + tid + t * 256;
      if (g < a.n) s += a.deg[g];
    }
    red[tid] = s;
    __syncthreads();
    for (int ofs = 128; ofs > 0; ofs >>= 1) {
      if (tid < ofs) red[tid] += red[tid + ofs];
      __syncthreads();
    }
    if (tid == 0) a.bsum[b] = red[0];
    return;
  }
  b -= a.nb;
  if (b < a.ms_blocks) {  // mask token scatter into bf16 H
    int gid = b * 256 + tid;
    if (gid >= a.nmask * 32) return;
    int i = gid >> 5;
    int c4 = (gid & 31) << 2;
    int r = a.mn[i];
    float4 t = *(const float4*)(a.token + c4);
    *(uint2*)(a.H + (size_t)r * 128 + c4) = f4_to_bf4(t);
    return;
  }
  b -= a.ms_blocks;
  {  // split weights into hi/lo planes
    int m = 0;
    while (m < 11 && b >= a.boff[m + 1]) ++m;
    int i = ((b - a.boff[m]) * 256 + tid) * 4;
    if (i >= a.sw.n[m]) return;
    float4 v = *(const float4*)(a.sw.src[m] + i);
    unsigned short h[4], l[4];
    split_bf16(v.x, h[0], l[0]);
    split_bf16(v.y, h[1], l[1]);
    split_bf16(v.z, h[2], l[2]);
    split_bf16(v.w, h[3], l[3]);
    *(uint2*)(a.sw.dh[m] + i) = make_uint2((unsigned)h[0] | ((unsigned)h[1] << 16),
                                           (unsigned)h[2] | ((unsigned)h[3] << 16));
    *(uint2*)(a.sw.dl[m] + i) = make_uint2((unsigned)l[0] | ((unsigned)l[1] << 16),
                                           (unsigned)l[2] | ((unsigned)l[3] << 16));
  }
}

// ---------------------------------------------------------------------------
// ComboA: sections {chunkscan (inlined bsum-scan) | enc0 p-GEMM (TNT=8,K=128)}
struct ComboAArgs {
  const int* deg; const int* bsum; int* off; int n; int nb;  // chunkscan
  const unsigned short* A1; const unsigned short* Wh1; const unsigned short* Wl1;
  const float* bias; unsigned short* C; int nrows;           // gemm
};

__global__ __launch_bounds__(256) void comboA_kernel(ComboAArgs a) {
  __shared__ __align__(16) unsigned short Wh[128][136];
  __shared__ __align__(16) unsigned short Wl[128][136];
  __shared__ int part[256];
  __shared__ int basesh;
  int b = blockIdx.x;
  int tid = threadIdx.x;
  if (b < a.nb) {  // chunkscan with inlined bsum scan
    if (tid < 64) {
      int v = (tid < a.nb) ? a.bsum[tid] : 0;
      int incl = v;
#pragma unroll
      for (int ofs = 1; ofs < 64; ofs <<= 1) {
        int u = __shfl_up(incl, ofs, 64);
        if (tid >= ofs) incl += u;
      }
      if (tid == b) basesh = incl - v;
      if (b == 0 && tid == a.nb - 1) a.off[a.n] = incl;
    }
    int base = b * SCAN_CHUNK;
    int g0 = base + tid * 4;
    int loc[4];
    int s = 0;
#pragma unroll
    for (int j = 0; j < 4; ++j) {
      int g = g0 + j;
      int d = (g < a.n) ? a.deg[g] : 0;
      loc[j] = s;
      s += d;
    }
    part[tid] = s;
    __syncthreads();
    for (int ofs = 1; ofs < 256; ofs <<= 1) {
      int v = 0;
      if (tid >= ofs) v = part[tid - ofs];
      __syncthreads();
      if (tid >= ofs) part[tid] += v;
      __syncthreads();
    }
    int pre = (tid == 0) ? 0 : part[tid - 1];
    int bb = basesh + pre;
#pragma unroll
    for (int j = 0; j < 4; ++j) {
      int g = g0 + j;
      if (g < a.n) a.off[g] = bb + loc[j];
    }
    return;
  }
  b -= a.nb;
  // enc0 p GEMM: pool = relu(h0 @ Wp0^T + b), 128x128
  constexpr int K = 128;
  const int lane = tid & 63;
  const int wv = tid >> 6;
  const int lr = lane & 15;
  const int lg = lane >> 4;
  const int row0 = b * 64;
  const int gra = row0 + wv * 16 + lr;

  f32x4 acc[8];
#pragma unroll
  for (int t = 0; t < 8; ++t) acc[t] = (f32x4)(0.f);

  {
    int tot8 = 128 * K / 8;
    for (int i = tid; i < tot8; i += 256) {
      int e0 = i * 8;
      int col = e0 / K;
      int kk = e0 - col * K;
      *(uint4*)&Wh[col][kk] = *(const uint4*)(a.Wh1 + e0);
      *(uint4*)&Wl[col][kk] = *(const uint4*)(a.Wl1 + e0);
    }
  }
  __syncthreads();

  for (int cb = 0; cb < K; cb += 32) {
    i32x4 a_h = (i32x4)(0);
    if (gra < a.nrows) a_h = *(const i32x4*)(a.A1 + (size_t)gra * K + cb + lg * 8);
#pragma unroll
    for (int t = 0; t < 8; ++t) {
      i32x4 b_h = *(const i32x4*)&Wh[t * 16 + lr][cb + lg * 8];
      i32x4 b_l = *(const i32x4*)&Wl[t * 16 + lr][cb + lg * 8];
      mfma_b16(acc[t], a_h, b_h);
      mfma_b16(acc[t], a_h, b_l);
    }
  }

  asm volatile("s_nop 7\n\ts_nop 7" ::);

#pragma unroll
  for (int t = 0; t < 8; ++t) {
    int c = t * 16 + lr;
    float bv = a.bias[c];
#pragma unroll
    for (int q = 0; q < 4; ++q) {
      int r = row0 + wv * 16 + lg * 4 + q;
      if (r < a.nrows) {
        float v = fmaxf(acc[t][q] + bv, 0.f);
        a.C[(size_t)r * 128 + c] = f2bf_rne(v);
      }
    }
  }
}

// ---------------------------------------------------------------------------
// scatter standalone (full occupancy: 4 VGPR, no LDS)
__global__ __launch_bounds__(256) void scatter_kernel(const int* __restrict__ src,
                                                      const int* __restrict__ dst,
                                                      const float* __restrict__ ew,
                                                      const int* __restrict__ off,
                                                      int* __restrict__ cur,
                                                      int2* __restrict__ esw, int nE) {
  int e = blockIdx.x * 256 + threadIdx.x;
  if (e >= nE) return;
  int d = dst[e];
  int pos = off[d] + atomicAdd(cur + d, 1);
  esw[pos] = make_int2(src[e], __float_as_int(ew[e]));
}

// ---------------------------------------------------------------------------
// neigh body: per-node segment max, din/8 lanes per node, uint4 loads
__device__ inline void neigh_body(int gid, const unsigned short* P, const int* off,
                                  const int2* esw, unsigned short* neigh,
                                  int din, int lanes, int nN) {
  int v = gid / lanes;
  int c = (gid - v * lanes) << 3;
  if (v >= nN) return;
  int jlo = off[v], jhi = off[v + 1];
  float m[8];
#pragma unroll
  for (int t = 0; t < 8; ++t) m[t] = 0.f;
  float n1[8], n2[8], n3[8];
#pragma unroll
  for (int t = 0; t < 8; ++t) { n1[t] = 0.f; n2[t] = 0.f; n3[t] = 0.f; }
  int j = jlo;
  for (; j + 4 <= jhi; j += 4) {
    int2 e0 = esw[j], e1 = esw[j + 1], e2 = esw[j + 2], e3 = esw[j + 3];
    uint4 q0 = *(const uint4*)(P + (size_t)e0.x * din + c);
    uint4 q1 = *(const uint4*)(P + (size_t)e1.x * din + c);
    uint4 q2 = *(const uint4*)(P + (size_t)e2.x * din + c);
    uint4 q3 = *(const uint4*)(P + (size_t)e3.x * din + c);
    float w0 = __int_as_float(e0.y), w1 = __int_as_float(e1.y);
    float w2 = __int_as_float(e2.y), w3 = __int_as_float(e3.y);
    float4 a0 = bf4_to_f4(make_uint2(q0.x, q0.y)), b0 = bf4_to_f4(make_uint2(q0.z, q0.w));
    float4 a1 = bf4_to_f4(make_uint2(q1.x, q1.y)), b1 = bf4_to_f4(make_uint2(q1.z, q1.w));
    float4 a2 = bf4_to_f4(make_uint2(q2.x, q2.y)), b2 = bf4_to_f4(make_uint2(q2.z, q2.w));
    float4 a3 = bf4_to_f4(make_uint2(q3.x, q3.y)), b3 = bf4_to_f4(make_uint2(q3.z, q3.w));
    m[0] = fmaxf(m[0], a0.x * w0); m[1] = fmaxf(m[1], a0.y * w0);
    m[2] = fmaxf(m[2], a0.z * w0); m[3] = fmaxf(m[3], a0.w * w0);
    m[4] = fmaxf(m[4], b0.x * w0); m[5] = fmaxf(m[5], b0.y * w0);
    m[6] = fmaxf(m[6], b0.z * w0); m[7] = fmaxf(m[7], b0.w * w0);
    n1[0] = fmaxf(n1[0], a1.x * w1); n1[1] = fmaxf(n1[1], a1.y * w1);
    n1[2] = fmaxf(n1[2], a1.z * w1); n1[3] = fmaxf(n1[3], a1.w * w1);
    n1[4] = fmaxf(n1[4], b1.x * w1); n1[5] = fmaxf(n1[5], b1.y * w1);
    n1[6] = fmaxf(n1[6], b1.z * w1); n1[7] = fmaxf(n1[7], b1.w * w1);
    n2[0] = fmaxf(n2[0], a2.x * w2); n2[1] = fmaxf(n2[1], a2.y * w2);
    n2[2] = fmaxf(n2[2], a2.z * w2); n2[3] = fmaxf(n2[3], a2.w * w2);
    n2[4] = fmaxf(n2[4], b2.x * w2); n2[5] = fmaxf(n2[5], b2.y * w2);
    n2[6] = fmaxf(n2[6], b2.z * w2); n2[7] = fmaxf(n2[7], b2.w * w2);
    n3[0] = fmaxf(n3[0], a3.x * w3); n3[1] = fmaxf(n3[1], a3.y * w3);
    n3[2] = fmaxf(n3[2], a3.z * w3); n3[3] = fmaxf(n3[3], a3.w * w3);
    n3[4] = fmaxf(n3[4], b3.x * w3); n3[5] = fmaxf(n3[5], b3.y * w3);
    n3[6] = fmaxf(n3[6], b3.z * w3); n3[7] = fmaxf(n3[7], b3.w * w3);
  }
  for (; j < jhi; ++j) {
    int2 e = esw[j];
    float w = __int_as_float(e.y);
    uint4 q = *(const uint4*)(P + (size_t)e.x * din + c);
    float4 a = bf4_to_f4(make_uint2(q.x, q.y)), b = bf4_to_f4(make_uint2(q.z, q.w));
    m[0] = fmaxf(m[0], a.x * w); m[1] = fmaxf(m[1], a.y * w);
    m[2] = fmaxf(m[2], a.z * w); m[3] = fmaxf(m[3], a.w * w);
    m[4] = fmaxf(m[4], b.x * w); m[5] = fmaxf(m[5], b.y * w);
    m[6] = fmaxf(m[6], b.z * w); m[7] = fmaxf(m[7], b.w * w);
  }
#pragma unroll
  for (int t = 0; t < 8; ++t) m[t] = fmaxf(fmaxf(m[t], n1[t]), fmaxf(n2[t], n3[t]));
  uint2 o0 = f4_to_bf4(make_float4(m[0], m[1], m[2], m[3]));
  uint2 o1 = f4_to_bf4(make_float4(m[4], m[5], m[6], m[7]));
  *(uint4*)(neigh + (size_t)v * din + c) = make_uint4(o0.x, o0.y, o1.x, o1.y);
}

__global__ __launch_bounds__(256) void neigh_csr_kernel(
    const unsigned short* __restrict__ P, const int* __restrict__ off,
    const int2* __restrict__ esw,
    unsigned short* __restrict__ neigh, int din, int lanes, int nN) {
  int gid = blockIdx.x * 256 + threadIdx.x;
  neigh_body(gid, P, off, esw, neigh, din, lanes, nN);
}

// ---------------------------------------------------------------------------
// ComboB: sections {neigh(din=64) | nodepred_ln}
struct ComboBArgs {
  const unsigned short* P; const int* off; const int2* esw;
  unsigned short* neigh; int nN; int ng_blocks;
  const unsigned short* H; const float* Wnp; const float* bnp;
  const float* g; const float* lb; float* out;
};

__global__ __launch_bounds__(256) void comboB_kernel(ComboBArgs a) {
  __shared__ float hs[16][64];
  int b = blockIdx.x;
  int tid = threadIdx.x;
  if (b < a.ng_blocks) {
    neigh_body(b * 256 + tid, a.P, a.off, a.esw, a.neigh, 64, 8, a.nN);
    return;
  }
  b -= a.ng_blocks;
  int row0 = b * 16;
  {
    int r = tid >> 4;
    int c4 = (tid & 15) << 2;
    int gr = row0 + r;
    float4 v = make_float4(0.f, 0.f, 0.f, 0.f);
    if (gr < a.nN) v = bf4_to_f4(*(const uint2*)(a.H + (size_t)gr * 64 + c4));
    *(float4*)&hs[r][c4] = v;
  }
  __syncthreads();
  int r = tid >> 4, j = tid & 15;
  float z = a.bnp[j];
  const float* wrow = a.Wnp + j * 64;
#pragma unroll 8
  for (int k = 0; k < 64; ++k) z += hs[r][k] * wrow[k];
  float s = z, s2 = z * z;
#pragma unroll
  for (int m = 1; m < 16; m <<= 1) {
    s += __shfl_xor(s, m, 16);
    s2 += __shfl_xor(s2, m, 16);
  }
  float mu = s * (1.f / 16.f);
  float var = s2 * (1.f / 16.f) - mu * mu;
  float o = (z - mu) * rsqrtf(var + EPS_LN) * a.g[j] + a.lb[j];
  int gr = row0 + r;
  if (gr < a.nN) a.out[(size_t)gr * 16 + j] = o;
}

// ---------------------------------------------------------------------------
// Fused SAGE out-GEMM + next-layer p-GEMM. WS templated on max(K, BN)+8 so
// smaller layers use less LDS (more blocks/CU). Block-local phase 3, no fence.
template <int TNT, int WS>  // BN = TNT*16
__global__ __launch_bounds__(256) void mfma_gemm_fused_kernel(
    const unsigned short* __restrict__ A1, const unsigned short* __restrict__ Wh1,
    const unsigned short* __restrict__ Wl1,
    const unsigned short* __restrict__ A2, const unsigned short* __restrict__ Wh2,
    const unsigned short* __restrict__ Wl2, int K,
    const float* __restrict__ bias, unsigned short* __restrict__ C,
    const unsigned short* __restrict__ pWh, const unsigned short* __restrict__ pWl,
    const float* __restrict__ pBias, unsigned short* __restrict__ P_out,
    int nrows) {
  constexpr int BN = TNT * 16;
  __shared__ __align__(16) unsigned short Wh[BN][WS];
  __shared__ __align__(16) unsigned short Wl[BN][WS];

  const int tid = threadIdx.x;
  const int lane = tid & 63;
  const int wv = tid >> 6;
  const int lr = lane & 15;
  const int lg = lane >> 4;
  const int row0 = blockIdx.x * 64;
  const int gra = row0 + wv * 16 + lr;

  f32x4 acc[TNT];
#pragma unroll
  for (int t = 0; t < TNT; ++t) acc[t] = (f32x4)(0.f);

  for (int pass = 0; pass < 2; ++pass) {
    const unsigned short* A = pass ? A2 : A1;
    const unsigned short* Whp = pass ? Wh2 : Wh1;
    const unsigned short* Wlp = pass ? Wl2 : Wl1;

    if (pass) __syncthreads();
    {
      int tot8 = BN * K / 8;
      for (int i = tid; i < tot8; i += 256) {
        int e0 = i * 8;
        int col = e0 / K;
        int kk = e0 - col * K;
        *(uint4*)&Wh[col][kk] = *(const uint4*)(Whp + e0);
        *(uint4*)&Wl[col][kk] = *(const uint4*)(Wlp + e0);
      }
    }
    __syncthreads();

    for (int cb = 0; cb < K; cb += 32) {
      i32x4 a_h = (i32x4)(0);
      if (gra < nrows) a_h = *(const i32x4*)(A + (size_t)gra * K + cb + lg * 8);
#pragma unroll
      for (int t = 0; t < TNT; ++t) {
        i32x4 b_h = *(const i32x4*)&Wh[t * 16 + lr][cb + lg * 8];
        i32x4 b_l = *(const i32x4*)&Wl[t * 16 + lr][cb + lg * 8];
        mfma_b16(acc[t], a_h, b_h);
        mfma_b16(acc[t], a_h, b_l);
      }
    }
  }

  asm volatile("s_nop 7\n\ts_nop 7" ::);

#pragma unroll
  for (int t = 0; t < TNT; ++t) {
    int c = t * 16 + lr;
    float bv = bias[c];
#pragma unroll
    for (int q = 0; q < 4; ++q) {
      int r = row0 + wv * 16 + lg * 4 + q;
      if (r < nrows) {
        float v = fmaxf(acc[t][q] + bv, 0.f);
        C[(size_t)r * BN + c] = f2bf_rne(v);
      }
    }
  }

  if (P_out == nullptr) return;

  // phase 3: p_next = relu(C @ Wp^T + pBias); block-local C rows only
  __syncthreads();
  {
    int tot8 = BN * BN / 8;
    for (int i = tid; i < tot8; i += 256) {
      int e0 = i * 8;
      int col = e0 / BN;
      int kk = e0 - col * BN;
      *(uint4*)&Wh[col][kk] = *(const uint4*)(pWh + e0);
      *(uint4*)&Wl[col][kk] = *(const uint4*)(pWl + e0);
    }
  }
  __syncthreads();

#pragma unroll
  for (int t = 0; t < TNT; ++t) acc[t] = (f32x4)(0.f);

  for (int cb = 0; cb < BN; cb += 32) {
    i32x4 a_h = (i32x4)(0);
    if (gra < nrows) a_h = *(const i32x4*)(C + (size_t)gra * BN + cb + lg * 8);
#pragma unroll
    for (int t = 0; t < TNT; ++t) {
      i32x4 b_h = *(const i32x4*)&Wh[t * 16 + lr][cb + lg * 8];
      i32x4 b_l = *(const i32x4*)&Wl[t * 16 + lr][cb + lg * 8];
      mfma_b16(acc[t], a_h, b_h);
      mfma_b16(acc[t], a_h, b_l);
    }
  }

  asm volatile("s_nop 7\n\ts_nop 7" ::);

#pragma unroll
  for (int t = 0; t < TNT; ++t) {
    int c = t * 16 + lr;
    float bv = pBias[c];
#pragma unroll
    for (int q = 0; q < 4; ++q) {
      int r = row0 + wv * 16 + lg * 4 + q;
      if (r < nrows) {
        float v = fmaxf(acc[t][q] + bv, 0.f);
        P_out[(size_t)r * BN + c] = f2bf_rne(v);
      }
    }
  }
}

// ---------------------------------------------------------------------------
__global__ __launch_bounds__(256) void gather_out_kernel(
    const int* __restrict__ mn, const unsigned short* __restrict__ R,
    const float* __restrict__ X,
    float* __restrict__ o1, float* __restrict__ o2, int nmask) {
  int gid = blockIdx.x * 256 + threadIdx.x;
  if (gid >= nmask * 32) return;
  int i = gid >> 5, c4 = (gid & 31) << 2;
  int r = mn[i];
  float4 rv = bf4_to_f4(*(const uint2*)(R + (size_t)r * 128 + c4));
  *(float4*)(o1 + (size_t)i * 128 + c4) = rv;
  *(float4*)(o2 + (size_t)i * 128 + c4) = *(const float4*)(X + (size_t)r * 128 + c4);
}

// ---------------------------------------------------------------------------
extern "C" void kernel_launch(void* const* d_in, const int* in_sizes, int n_in,
                              void* d_out, int out_size, void* d_ws, size_t ws_size,
                              hipStream_t stream) {
  const float* x = (const float*)d_in[0];
  const int* src = (const int*)d_in[1];
  const int* dst = (const int*)d_in[2];
  const float* ew = (const float*)d_in[3];
  const int* mn = (const int*)d_in[4];
  const float* token = (const float*)d_in[5];

  const float* W[20];
  for (int i = 0; i < 20; ++i) W[i] = (const float*)d_in[6 + i];
  const float* W_e2d = (const float*)d_in[26];
  const float* Wnp = (const float*)d_in[27];
  const float* bnp = (const float*)d_in[28];
  const float* ln_g = (const float*)d_in[29];
  const float* ln_b = (const float*)d_in[30];

  const int Nn = in_sizes[0] / 128;   // 50000
  const int E = in_sizes[1];          // 600000
  const int nmask = in_sizes[4];      // 10000
  const int nb = (Nn + SCAN_CHUNK - 1) / SCAN_CHUNK;  // 49

  // workspace layout (bf16 activations)
  unsigned short* bufA = (unsigned short*)d_ws;            // N*128 bf16
  unsigned short* bufB = bufA + (size_t)Nn * 128;          // N*128 bf16
  unsigned short* pool16 = bufB + (size_t)Nn * 128;        // N*128 bf16
  unsigned short* neigh16 = pool16 + (size_t)Nn * 128;     // N*128 bf16
  int* deg = (int*)(neigh16 + (size_t)Nn * 128);           // N int
  int* cur = deg + Nn;                                     // N int
  int2* esw = (int2*)(cur + Nn);                           // E int2
  int* off = (int*)(esw + E);                              // N+1 int
  int* bsum = off + Nn + 1;                                // 64 int
  float* WpP = (float*)(bsum + 64);                        // 64*64 f32
  float* WsP = WpP + 64 * 64;                              // 96*64 f32
  unsigned short* wplanes =
      (unsigned short*)(((uintptr_t)(WsP + 96 * 64) + 15) & ~(uintptr_t)15);

  // plane table
  const int msz[12] = {128 * 128, 96 * 128, 96 * 128, 96 * 96, 64 * 96, 64 * 96,
                       64 * 64,  96 * 64,  96 * 64,  96 * 96, 128 * 96, 128 * 96};
  const float* msrc[12] = {W[0], W[2], W[3], W[5], W[7], W[8],
                           WpP,  WsP,  W[13], W[15], W[17], W[18]};
  int mtot = 0;
  int moff[12];
  for (int i = 0; i < 12; ++i) { moff[i] = mtot; mtot += msz[i]; }
  unsigned short* wh_[12];
  unsigned short* wl_[12];
  for (int i = 0; i < 12; ++i) {
    wh_[i] = wplanes + moff[i];
    wl_[i] = wplanes + mtot + moff[i];
  }

  // ---- dispatch 1: zero deg+cur ----
  hipMemsetAsync(deg, 0, (size_t)Nn * 2 * sizeof(int), stream);

  // ---- dispatch 2: prep1 ----
  Prep1Args p1;
  p1.x4 = (const float4*)x;
  p1.h_out = (uint2*)bufA;
  p1.n4 = Nn * 128 / 4;
  p1.cb_blocks = (p1.n4 + 255) / 256;
  p1.dst = dst;
  p1.deg = deg;
  p1.nE = E;
  p1.hist_blocks = (E + 255) / 256;
  p1.W10 = W[10]; p1.We2d = W_e2d; p1.WpP = WpP;
  p1.W12 = W[12]; p1.WsP = WsP;
  int p1_blocks = p1.cb_blocks + p1.hist_blocks + 16 + 24;
  prep1_kernel<<<p1_blocks, 256, 0, stream>>>(p1);

  // ---- dispatch 3: prep2 ----
  Prep2Args p2;
  p2.deg = deg; p2.bsum = bsum; p2.n = Nn; p2.nb = nb;
  p2.mn = mn; p2.token = token; p2.H = bufA; p2.nmask = nmask;
  p2.ms_blocks = (nmask * 32 + 255) / 256;
  for (int i = 0; i < 12; ++i) {
    p2.sw.src[i] = msrc[i];
    p2.sw.dh[i] = wh_[i];
    p2.sw.dl[i] = wl_[i];
    p2.sw.n[i] = msz[i];
  }
  p2.boff[0] = 0;
  for (int i = 0; i < 12; ++i) p2.boff[i + 1] = p2.boff[i] + (msz[i] / 4 + 255) / 256;
  int p2_blocks = p2.nb + p2.ms_blocks + p2.boff[12];
  prep2_kernel<<<p2_blocks, 256, 0, stream>>>(p2);

  int gblocks = (Nn + 63) / 64;

  // ---- dispatch 4: comboA = chunkscan || enc0 p-GEMM ----
  ComboAArgs ca;
  ca.deg = deg; ca.bsum = bsum; ca.off = off; ca.n = Nn; ca.nb = nb;
  ca.A1 = bufA; ca.Wh1 = wh_[0]; ca.Wl1 = wl_[0];
  ca.bias = W[1]; ca.C = pool16; ca.nrows = Nn;
  comboA_kernel<<<nb + gblocks, 256, 0, stream>>>(ca);

  // ---- dispatch 5: scatter (full occupancy) ----
  scatter_kernel<<<(E + 255) / 256, 256, 0, stream>>>(src, dst, ew, off, cur, esw, E);

  auto neigh = [&](int din) {
    int lanes = din >> 3;
    long long tot = (long long)Nn * lanes;
    int nblocks = (int)((tot + 255) / 256);
    neigh_csr_kernel<<<nblocks, 256, 0, stream>>>(pool16, off, esw, neigh16, din, lanes, Nn);
  };

  // ---- enc0: h1[96]; fused p_enc1 -> pool. K=128, p3 K=96 -> WS=136 ----
  neigh(128);
  mfma_gemm_fused_kernel<6, 136><<<gblocks, 256, 0, stream>>>(
      bufA, wh_[1], wl_[1], neigh16, wh_[2], wl_[2], 128, W[4], bufB,
      wh_[3], wl_[3], W[6], pool16, Nn);

  // ---- enc1: h2[64]; fused p_dec0 -> pool. K=96, p3 K=64 -> WS=104 ----
  neigh(96);
  mfma_gemm_fused_kernel<4, 104><<<gblocks, 256, 0, stream>>>(
      bufB, wh_[4], wl_[4], neigh16, wh_[5], wl_[5], 96, W[9], bufA,
      wh_[6], wl_[6], W[11], pool16, Nn);

  float* out_r = (float*)d_out;
  float* out_x = out_r + (size_t)nmask * 128;
  float* out_ns = out_x + (size_t)nmask * 128;

  // ---- comboB = neigh(64) || nodepred_ln(h2) ----
  ComboBArgs cb;
  cb.P = pool16; cb.off = off; cb.esw = esw; cb.neigh = neigh16; cb.nN = Nn;
  cb.ng_blocks = (Nn * 8 + 255) / 256;
  cb.H = bufA; cb.Wnp = Wnp; cb.bnp = bnp; cb.g = ln_g; cb.lb = ln_b; cb.out = out_ns;
  int np_blocks = (Nn + 15) / 16;
  comboB_kernel<<<cb.ng_blocks + np_blocks, 256, 0, stream>>>(cb);

  // ---- dec0: h3[96]; fused p_dec1 -> pool. K=64, p3 K=96 -> WS=104 ----
  mfma_gemm_fused_kernel<6, 104><<<gblocks, 256, 0, stream>>>(
      bufA, wh_[7], wl_[7], neigh16, wh_[8], wl_[8], 64, W[14], bufB,
      wh_[9], wl_[9], W[16], pool16, Nn);

  // ---- dec1: h4[128], no p3. K=96 -> WS=104 ----
  neigh(96);
  mfma_gemm_fused_kernel<8, 104><<<gblocks, 256, 0, stream>>>(
      bufB, wh_[10], wl_[10], neigh16, wh_[11], wl_[11], 96, W[19], bufA,
      nullptr, nullptr, nullptr, nullptr, Nn);

  // outputs 1 & 2
  gather_out_kernel<<<(nmask * 32 + 255) / 256, 256, 0, stream>>>(mn, bufA, x, out_r, out_x, nmask);
}